// Round 3
// baseline (7444.375 us; speedup 1.0000x reference)
//
#include <hip/hip_runtime.h>
#include <math.h>

// MultiScaleCodebook on MI355X — round 3: conflict-free argmin + fusion.
// r2 post-mortem: argmin had 5.2M LDS bank-conflict cycles (restT column
// writes -> 4 banks, 16-way). Fix: pool emits a global transposed rest32T
// so argmin stages with pure b128 2-way (free) access. Argmin re-blocked to
// 64p x 128j (4x8 acc/thread, 3 b128 per 32 FMA -> FMA-bound). reduce+refine
// fused (block-local flags). Conv weights staged fp32 (exact), halving LDS
// reads. Numeric chain identical to r2: fp64 pool/upsample/conv/refine,
// fp32 pass-1 distances with 0.01 top-2 margin -> fp64 full rescan.

#define NCODES 16384
#define NELEM  524288   // 8*64*4*16*16
#define NSP    8192     // 8*4*16*16

// workspace byte offsets (total ~27.1 MB)
#define WS_ACCU   0ul
#define WS_HUP    4194304ul
#define WS_REST64 8388608ul
#define WS_PART   12582912ul
#define WS_ZCL    16777216ul
#define WS_ET     18874368ul
#define WS_ESQ    23068672ul
#define WS_TWT    23134208ul
#define WS_IDX    24903680ul
#define WS_CNT    24936448ul
#define WS_SSE    25034816ul
#define WS_ENT    25034824ul
#define WS_USED   25034832ul
#define WS_R32T   25034848ul   // rest32T [64][NSpad] fp32, <= 2 MB

// ---------------------------------------------------------------- prep
__global__ __launch_bounds__(256) void prep_kernel(
    const float* __restrict__ z, const float* __restrict__ emb, const float* __restrict__ Wq,
    double* __restrict__ accu, float* __restrict__ zcl, float* __restrict__ et,
    float* __restrict__ esq, float* __restrict__ twt,
    int* __restrict__ counts, double* sse, double* ent, int* usedcnt)
{
  int i = blockIdx.x * 256 + threadIdx.x;
  if (i < NELEM) { accu[i] = 0.0; return; }
  i -= NELEM;
  if (i < NELEM) {  // z [B,C,T,H,W] -> zcl [B,T,H,W,C]
    int c = i & 63, w = (i >> 6) & 15, h = (i >> 10) & 15, t = (i >> 14) & 3, b = i >> 16;
    zcl[i] = z[(((b * 64 + c) * 4 + t) * 16 + h) * 16 + w];
    return;
  }
  i -= NELEM;
  if (i < NCODES * 64) {  // et[c][j] = emb[j][c]
    int j = i & (NCODES - 1); int c = i >> 14;
    et[i] = emb[j * 64 + c];
    return;
  }
  i -= NCODES * 64;
  if (i < NCODES) {  // e_sq fp32 (ranking only; refine is fp64)
    float s = 0.f;
    for (int c = 0; c < 64; c++) { float v = emb[i * 64 + c]; s += v * v; }
    esq[i] = s; return;
  }
  i -= NCODES;
  if (i < 442368) {  // twt[qi][tap][ci][co] = Wq[qi][co][ci][tap]
    int qi = i / 110592; int r = i % 110592;
    int tap = r >> 12; int ci = (r >> 6) & 63; int co = r & 63;
    twt[i] = Wq[((qi * 64 + co) * 64 + ci) * 27 + tap];
    return;
  }
  i -= 442368;
  if (i < NCODES) { counts[i] = 0; return; }
  i -= NCODES;
  if (i < 4) {
    if (i == 0) *sse = 0.0;
    else if (i == 1) *ent = 0.0;
    else if (i == 2) *usedcnt = 0;
  }
}

// ------------------------------------------- pool (area) + global transpose
// grid NSpad/64 blocks; block: 64 points x 64 ch. Writes rest64[p][c] (fp64,
// for refine) and rest32T[c][p] (fp32, argmin staging layout).
__global__ __launch_bounds__(256) void pool_kernel(
    const float* __restrict__ zcl, const double* __restrict__ accu,
    double* __restrict__ rest64, float* __restrict__ rest32T,
    int N, int NS, int tpn, int pn)
{
  __shared__ double tile[64][65];
  int tid = threadIdx.x;
  int pbase = blockIdx.x * 64;
  int ppn = pn * pn;
#pragma unroll
  for (int it = 0; it < 16; it++) {
    int pi = it * 256 + tid;
    int pl = pi >> 6, c = pi & 63;
    int n = pbase + pl;
    double rv = 0.0;
    if (n < N) {
      int b = n / (tpn * ppn); int r = n % (tpn * ppn);
      int u = r / ppn; r %= ppn; int v = r / pn; int x = r % pn;
      int t0 = (u * 4) / tpn, t1 = ((u + 1) * 4 + tpn - 1) / tpn;
      int h0 = (v * 16) / pn, h1 = ((v + 1) * 16 + pn - 1) / pn;
      int w0 = (x * 16) / pn, w1 = ((x + 1) * 16 + pn - 1) / pn;
      double s = 0.0;
      for (int t = t0; t < t1; t++)
        for (int h = h0; h < h1; h++)
          for (int w = w0; w < w1; w++) {
            size_t off = (size_t)((((b * 4 + t) * 16 + h) * 16 + w) * 64 + c);
            s += (double)zcl[off] - accu[off];
          }
      // pool-matrix entries are fp32(1/n) used in fp64 (matches np ref)
      float wt = 1.f / (float)(t1 - t0), wh = 1.f / (float)(h1 - h0), ww = 1.f / (float)(w1 - w0);
      rv = s * (double)wt * (double)wh * (double)ww;
      rest64[(size_t)n * 64 + c] = rv;
    }
    tile[pl][c] = rv;
  }
  __syncthreads();
#pragma unroll
  for (int it = 0; it < 16; it++) {
    int pi = it * 256 + tid;
    int c2 = pi >> 6, p2 = pi & 63;
    rest32T[(size_t)c2 * NS + pbase + p2] = (float)tile[p2][c2];
  }
}

// ------------------------------------------------- argmin pass 1 (fp32 GEMM)
// grid (NS/64, 16): 64 points x 1024-code chunk; 8 tiles of 128 codes.
// Thread = 4p x 8j. Top-2 (value,index) per point with margin for refine.
__global__ __launch_bounds__(256) void argmin_kernel(
    const float* __restrict__ rest32T, const float* __restrict__ et,
    const float* __restrict__ esq, float4* __restrict__ part, int NS)
{
  __shared__ __align__(16) float restT[64][64];   // [k][p]  16 KB
  __shared__ __align__(16) float etile[64][128];  // [k][j]  32 KB
  int tid = threadIdx.x;
  int pbase = blockIdx.x * 64;
  int ch = blockIdx.y;
#pragma unroll
  for (int it = 0; it < 4; it++) {
    int i2 = (tid + it * 256) * 4;
    int k = i2 >> 6, p4 = i2 & 63;
    *(float4*)&restT[k][p4] = *(const float4*)&rest32T[(size_t)k * NS + pbase + p4];
  }
  int tx = tid & 15, ty = tid >> 4;
  float m1[4], m2[4]; int i1[4];
#pragma unroll
  for (int r = 0; r < 4; r++) { m1[r] = 3.4e38f; m2[r] = 3.4e38f; i1[r] = 0x7fffffff; }
  for (int tile = 0; tile < 8; tile++) {
    int j0 = ch * 1024 + tile * 128;
    __syncthreads();
#pragma unroll
    for (int it = 0; it < 8; it++) {
      int i2 = (tid + it * 256) * 4;
      int k = i2 >> 7, jj = i2 & 127;
      *(float4*)&etile[k][jj] = *(const float4*)&et[(size_t)k * NCODES + j0 + jj];
    }
    __syncthreads();
    float acc[4][8];
#pragma unroll
    for (int r = 0; r < 4; r++)
#pragma unroll
      for (int q = 0; q < 8; q++) acc[r][q] = 0.f;
#pragma unroll 8
    for (int k = 0; k < 64; k++) {
      float4 a  = *(const float4*)&restT[k][ty * 4];
      float4 b0 = *(const float4*)&etile[k][tx * 8];
      float4 b1 = *(const float4*)&etile[k][tx * 8 + 4];
      float av[4] = {a.x, a.y, a.z, a.w};
      float bv[8] = {b0.x, b0.y, b0.z, b0.w, b1.x, b1.y, b1.z, b1.w};
#pragma unroll
      for (int r = 0; r < 4; r++)
#pragma unroll
        for (int q = 0; q < 8; q++) acc[r][q] += av[r] * bv[q];
    }
#pragma unroll
    for (int q = 0; q < 8; q++) {
      int j = j0 + tx * 8 + q;
      float es = esq[j];
#pragma unroll
      for (int r = 0; r < 4; r++) {
        float d = es - 2.f * acc[r][q];  // ||z||^2 shift is argmin-invariant
        if (d < m1[r]) { m2[r] = m1[r]; m1[r] = d; i1[r] = j; }
        else if (d < m2[r]) { m2[r] = d; }
      }
    }
  }
  // reduce top-2 across the 16 tx lanes (same wave, same 4 points)
#pragma unroll
  for (int off = 1; off < 16; off <<= 1) {
#pragma unroll
    for (int r = 0; r < 4; r++) {
      float o1 = __shfl_xor(m1[r], off);
      int   oi = __shfl_xor(i1[r], off);
      float o2 = __shfl_xor(m2[r], off);
      bool bwin = (o1 < m1[r]) || (o1 == m1[r] && oi < i1[r]);
      float nm2 = bwin ? fminf(m1[r], o2) : fminf(m2[r], o1);
      if (bwin) { m1[r] = o1; i1[r] = oi; }
      m2[r] = nm2;
    }
  }
  if (tx == 0) {
#pragma unroll
    for (int r = 0; r < 4; r++) {
      int n = pbase + ty * 4 + r;
      part[(size_t)ch * NSP + n] = make_float4(m1[r], m2[r], __int_as_float(i1[r]), 0.f);
    }
  }
}

// -------------------------------- merge chunks + block-local fp64 refine
__global__ __launch_bounds__(256) void reduce_refine_kernel(
    const float4* __restrict__ part, const double* __restrict__ rest64,
    const float* __restrict__ emb, int* __restrict__ idx_cur,
    float* __restrict__ out_idx, int N)
{
  __shared__ int lflag[256];
  __shared__ int lcnt;
  __shared__ double rl[64];
  __shared__ double bm[256];
  __shared__ int    bi[256];
  int tid = threadIdx.x;
  if (tid == 0) lcnt = 0;
  __syncthreads();
  int n = blockIdx.x * 256 + tid;
  if (n < N) {
    float m1 = 3.4e38f, m2 = 3.4e38f; int i1 = 0x7fffffff;
    for (int ch = 0; ch < 16; ch++) {
      float4 q = part[(size_t)ch * NSP + n];
      float o1 = q.x, o2 = q.y; int oi = __float_as_int(q.z);
      bool bwin = (o1 < m1) || (o1 == m1 && oi < i1);
      float nm2 = bwin ? fminf(m1, o2) : fminf(m2, o1);
      if (bwin) { m1 = o1; i1 = oi; }
      m2 = nm2;
    }
    idx_cur[n] = i1;
    out_idx[n] = (float)i1;
    if (m2 - m1 < 0.01f) {  // near-tie: fp32 noise could differ from fp64 ref
      int pos = atomicAdd(&lcnt, 1);
      lflag[pos] = n;
    }
  }
  __syncthreads();
  int cnt = lcnt;
  for (int f = 0; f < cnt; f++) {
    int nn = lflag[f];
    __syncthreads();
    if (tid < 64) rl[tid] = rest64[(size_t)nn * 64 + tid];
    __syncthreads();
    double best = 1e300; int bidx = 0x7fffffff;
    for (int j = tid; j < NCODES; j += 256) {
      double d = 0.0;
      for (int c = 0; c < 64; c++) { double df = rl[c] - (double)emb[(size_t)j * 64 + c]; d += df * df; }
      if (d < best) { best = d; bidx = j; }  // ascending j keeps first min
    }
    bm[tid] = best; bi[tid] = bidx;
    __syncthreads();
    for (int s = 128; s > 0; s >>= 1) {
      if (tid < s) {
        double ob = bm[tid + s]; int oi = bi[tid + s];
        if (ob < bm[tid] || (ob == bm[tid] && oi < bi[tid])) { bm[tid] = ob; bi[tid] = oi; }
      }
      __syncthreads();
    }
    if (tid == 0) { idx_cur[nn] = bi[0]; out_idx[nn] = (float)bi[0]; }
  }
}

// ------------------------------------------------------- trilinear upsample
__device__ inline void axis_map(int L, int outlen, int i, int* j0, int* j1, float* a0, float* a1) {
  if (L == 1) { *j0 = 0; *j1 = 0; *a0 = 1.f; *a1 = 0.f; return; }
  double scale = (double)L / (double)outlen;
  double src = (i + 0.5) * scale - 0.5;
  if (src < 0.0) src = 0.0;
  int i0 = (int)floor(src); if (i0 > L - 1) i0 = L - 1;
  int i1 = i0 + 1; if (i1 > L - 1) i1 = L - 1;
  double wv = src - (double)i0;
  if (i0 == i1) {
    float p = (float)(1.0 - wv), q = (float)wv;  // fp32 += emulation
    *a0 = p + q; *a1 = 0.f;
  } else { *a0 = (float)(1.0 - wv); *a1 = (float)wv; }
  *j0 = i0; *j1 = i1;
}

__global__ __launch_bounds__(256) void upsample_kernel(
    const float* __restrict__ emb, const int* __restrict__ idx_cur,
    double* __restrict__ hup, int tpn, int pn)
{
  int e = blockIdx.x * 256 + threadIdx.x;  // [b][t][h][w][c]
  int c = e & 63, w = (e >> 6) & 15, h = (e >> 10) & 15, t = (e >> 14) & 3, b = e >> 16;
  int t0, t1, h0, h1, w0, w1; float ta0, ta1, ha0, ha1, wa0, wa1;
  axis_map(tpn, 4, t, &t0, &t1, &ta0, &ta1);
  axis_map(pn, 16, h, &h0, &h1, &ha0, &ha1);
  axis_map(pn, 16, w, &w0, &w1, &wa0, &wa1);
  int ti[2] = {t0, t1}; float ta[2] = {ta0, ta1};
  int hi[2] = {h0, h1}; float ha[2] = {ha0, ha1};
  int wi[2] = {w0, w1}; float wa[2] = {wa0, wa1};
  double val = 0.0;
  for (int a = 0; a < 2; a++)
    for (int bb = 0; bb < 2; bb++)
      for (int cc = 0; cc < 2; cc++) {
        double wgt = (double)ta[a] * (double)ha[bb] * (double)wa[cc];
        if (wgt != 0.0) {
          int code = idx_cur[((b * tpn + ti[a]) * pn + hi[bb]) * pn + wi[cc]];
          val += wgt * (double)emb[(size_t)code * 64 + c];
        }
      }
  hup[e] = val;
}

// ------------------------------------------- conv3d + accu update + commit
// grid 256 = b*32 + t*8 + hq ; block: 16 w x 16 co-quads ; 2 h-rows/thread
__global__ __launch_bounds__(256) void conv_kernel(
    const double* __restrict__ hup, const float* __restrict__ twt, const float* __restrict__ bq,
    const float* __restrict__ zcl, double* __restrict__ accu, double* sse, int qi)
{
  __shared__ double hl[3][4][4][18];              // [tt][hh][cc][ww] halo, ci-chunk 4
  __shared__ __align__(16) float wl[27][4][64];   // [tap][cc][co] fp32 (exact)
  __shared__ double red[256];
  int bid = blockIdx.x;
  int b = bid >> 5, t = (bid >> 3) & 3, hq = bid & 7;
  int tid = threadIdx.x;
  int co4 = tid >> 4;  // co = co4*4 .. +3
  int w = tid & 15;
  double acc[2][4];
  for (int k = 0; k < 2; k++) for (int q = 0; q < 4; q++) acc[k][q] = 0.0;
  for (int ci0 = 0; ci0 < 64; ci0 += 4) {
    __syncthreads();
    for (int i = tid; i < 864; i += 256) {
      int ww = i % 18; int r = i / 18; int cc = r & 3; r >>= 2; int hh = r & 3; int tt = r >> 2;
      int gt = t - 1 + tt, gh = hq * 2 - 1 + hh, gw = ww - 1;
      double v = 0.0;
      if (gt >= 0 && gt < 4 && gh >= 0 && gh < 16 && gw >= 0 && gw < 16)
        v = hup[(size_t)((((b * 4 + gt) * 16 + gh) * 16 + gw) * 64 + ci0 + cc)];
      hl[tt][hh][cc][ww] = v;
    }
    for (int i = tid; i < 6912; i += 256) {
      int co = i & 63; int r = i >> 6; int cc = r & 3; int tap = r >> 2;
      wl[tap][cc][co] = twt[(size_t)(((qi * 27 + tap) * 64 + ci0 + cc) * 64 + co)];
    }
    __syncthreads();
    for (int tap = 0; tap < 27; tap++) {
      int dt = tap / 9, dh = (tap / 3) % 3, dw = tap % 3;
#pragma unroll
      for (int cc = 0; cc < 4; cc++) {
        float4 wf = *(const float4*)&wl[tap][cc][co4 * 4];
        double w0 = (double)wf.x, w1 = (double)wf.y, w2 = (double)wf.z, w3 = (double)wf.w;
#pragma unroll
        for (int k = 0; k < 2; k++) {
          double hv = hl[dt][k + dh][cc][w + dw];
          acc[k][0] += hv * w0; acc[k][1] += hv * w1;
          acc[k][2] += hv * w2; acc[k][3] += hv * w3;
        }
      }
    }
  }
  double lsse = 0.0;
  for (int k = 0; k < 2; k++) {
    int gh = hq * 2 + k;
    for (int q = 0; q < 4; q++) {
      int co = co4 * 4 + q;
      size_t off = (size_t)((((b * 4 + t) * 16 + gh) * 16 + w) * 64 + co);
      double conv = acc[k][q] + (double)bq[qi * 64 + co];
      double hu = hup[off];
      double na = accu[off] + 0.5 * hu + 0.5 * conv;  // h*(1-q) + conv*q, q=0.5
      accu[off] = na;
      double df = na - (double)zcl[off];
      lsse += df * df;
    }
  }
  red[tid] = lsse;
  __syncthreads();
  for (int s = 128; s > 0; s >>= 1) { if (tid < s) red[tid] += red[tid + s]; __syncthreads(); }
  if (tid == 0) atomicAdd(sse, red[0]);
}

// ---------------------------------------------------------------- stats
__global__ __launch_bounds__(256) void bincount_kernel(const int* __restrict__ idx_cur, int* counts) {
  int i = blockIdx.x * 256 + threadIdx.x;
  if (i < NSP) atomicAdd(&counts[idx_cur[i]], 1);
}

__global__ __launch_bounds__(256) void stats_kernel(
    const int* __restrict__ counts, float* __restrict__ usage_out, double* ent, int* usedcnt)
{
  __shared__ double re[256];
  __shared__ int ru[256];
  int j = blockIdx.x * 256 + threadIdx.x;
  int cnt = counts[j];
  double p = (double)cnt / 8192.0;
  usage_out[j] = (float)p;
  re[threadIdx.x] = p * log(p + 1e-10);
  ru[threadIdx.x] = cnt > 0 ? 1 : 0;
  __syncthreads();
  for (int s = 128; s > 0; s >>= 1) {
    if (threadIdx.x < s) { re[threadIdx.x] += re[threadIdx.x + s]; ru[threadIdx.x] += ru[threadIdx.x + s]; }
    __syncthreads();
  }
  if (threadIdx.x == 0) { atomicAdd(ent, re[0]); atomicAdd(usedcnt, ru[0]); }
}

__global__ void final_kernel(const double* sse, const double* ent, const int* usedcnt, float* out) {
  if (threadIdx.x == 0) {
    out[NELEM]     = (float)(*sse * 0.25 / 524288.0 / 10.0);
    out[NELEM + 1] = (float)exp(-*ent);
    out[NELEM + 2] = (float)((double)*usedcnt / 16384.0);
  }
}

__global__ __launch_bounds__(256) void embst_kernel(const double* __restrict__ accu, float* __restrict__ out) {
  int e = blockIdx.x * 256 + threadIdx.x;  // out [B,C,T,H,W]
  int w = e & 15, h = (e >> 4) & 15, t = (e >> 8) & 3, c = (e >> 10) & 63, b = e >> 16;
  out[e] = (float)accu[(size_t)(((((b * 4 + t) * 16 + h) * 16 + w) * 64) + c)];
}

// ---------------------------------------------------------------- launch
extern "C" void kernel_launch(void* const* d_in, const int* in_sizes, int n_in,
                              void* d_out, int out_size, void* d_ws, size_t ws_size,
                              hipStream_t stream) {
  static const int T_PN_h[10] = {1, 1, 2, 2, 2, 4, 4, 4, 4, 4};
  static const int V_PN_h[10] = {1, 2, 3, 4, 5, 6, 8, 10, 13, 16};
  // qi from bit-exact fp64 emulation of np.linspace+argmin (ties: si=2->1, si=7->3)
  static const int QI_h[10]   = {0, 0, 1, 1, 1, 2, 2, 3, 3, 3};
  static const int NS_h[10]   = {8, 32, 144, 256, 400, 1152, 2048, 3200, 5408, 8192};
  static const int OB_h[10]   = {540675, 540683, 540715, 540859, 541115,
                                 541515, 542667, 544715, 547915, 553323};

  const float* z   = (const float*)d_in[0];
  const float* emb = (const float*)d_in[1];
  const float* Wq  = (const float*)d_in[2];
  const float* bq  = (const float*)d_in[3];
  float* out = (float*)d_out;
  char* ws = (char*)d_ws;

  double* accu    = (double*)(ws + WS_ACCU);
  double* hup     = (double*)(ws + WS_HUP);
  double* rest64  = (double*)(ws + WS_REST64);
  float4* part    = (float4*)(ws + WS_PART);
  float*  zcl     = (float*)(ws + WS_ZCL);
  float*  et      = (float*)(ws + WS_ET);
  float*  esq     = (float*)(ws + WS_ESQ);
  float*  twt     = (float*)(ws + WS_TWT);
  int*    idx_cur = (int*)(ws + WS_IDX);
  int*    counts  = (int*)(ws + WS_CNT);
  double* sse     = (double*)(ws + WS_SSE);
  double* ent     = (double*)(ws + WS_ENT);
  int*    usedcnt = (int*)(ws + WS_USED);
  float*  rest32T = (float*)(ws + WS_R32T);

  prep_kernel<<<10049, 256, 0, stream>>>(z, emb, Wq, accu, zcl, et, esq, twt,
                                         counts, sse, ent, usedcnt);

  for (int si = 0; si < 10; si++) {
    int tpn = T_PN_h[si], pn = V_PN_h[si], N = NS_h[si];
    int NSpad = (N + 63) & ~63;
    pool_kernel<<<NSpad / 64, 256, 0, stream>>>(zcl, accu, rest64, rest32T, N, NSpad, tpn, pn);
    dim3 ag(NSpad / 64, 16);
    argmin_kernel<<<ag, 256, 0, stream>>>(rest32T, et, esq, part, NSpad);
    reduce_refine_kernel<<<(N + 255) / 256, 256, 0, stream>>>(part, rest64, emb, idx_cur,
                                                              out + OB_h[si], N);
    upsample_kernel<<<NELEM / 256, 256, 0, stream>>>(emb, idx_cur, hup, tpn, pn);
    conv_kernel<<<256, 256, 0, stream>>>(hup, twt, bq, zcl, accu, sse, QI_h[si]);
  }

  bincount_kernel<<<32, 256, 0, stream>>>(idx_cur, counts);
  stats_kernel<<<64, 256, 0, stream>>>(counts, out + 524291, ent, usedcnt);
  final_kernel<<<1, 64, 0, stream>>>(sse, ent, usedcnt, out);
  embst_kernel<<<NELEM / 256, 256, 0, stream>>>(accu, out);
}

// Round 4
// 5475.908 us; speedup vs baseline: 1.3595x; 1.3595x over previous
//
#include <hip/hip_runtime.h>
#include <math.h>

// MultiScaleCodebook on MI355X — round 4: re-parallelized pool.
// r3 post-mortem: pool regression (630us/dispatch, occupancy 0.05%) — each
// thread owned 16 (p,c) pairs x full-window serial loop, 1 block for small
// scales. Fix: one block per output point, 256 thr = 64 c x 4 window chunks,
// coalesced channel-major loads, deterministic chunk combine. argmin/conv
// unchanged from r3 (conflict-free staging, fp32-GEMM + fp64 refine chain).

#define NCODES 16384
#define NELEM  524288   // 8*64*4*16*16
#define NSP    8192     // 8*4*16*16

// workspace byte offsets (total ~27.1 MB)
#define WS_ACCU   0ul
#define WS_HUP    4194304ul
#define WS_REST64 8388608ul
#define WS_PART   12582912ul
#define WS_ZCL    16777216ul
#define WS_ET     18874368ul
#define WS_ESQ    23068672ul
#define WS_TWT    23134208ul
#define WS_IDX    24903680ul
#define WS_CNT    24936448ul
#define WS_SSE    25034816ul
#define WS_ENT    25034824ul
#define WS_USED   25034832ul
#define WS_R32T   25034848ul   // rest32T [64][NSpad] fp32, <= 2 MB

// ---------------------------------------------------------------- prep
__global__ __launch_bounds__(256) void prep_kernel(
    const float* __restrict__ z, const float* __restrict__ emb, const float* __restrict__ Wq,
    double* __restrict__ accu, float* __restrict__ zcl, float* __restrict__ et,
    float* __restrict__ esq, float* __restrict__ twt,
    int* __restrict__ counts, double* sse, double* ent, int* usedcnt)
{
  int i = blockIdx.x * 256 + threadIdx.x;
  if (i < NELEM) { accu[i] = 0.0; return; }
  i -= NELEM;
  if (i < NELEM) {  // z [B,C,T,H,W] -> zcl [B,T,H,W,C]
    int c = i & 63, w = (i >> 6) & 15, h = (i >> 10) & 15, t = (i >> 14) & 3, b = i >> 16;
    zcl[i] = z[(((b * 64 + c) * 4 + t) * 16 + h) * 16 + w];
    return;
  }
  i -= NELEM;
  if (i < NCODES * 64) {  // et[c][j] = emb[j][c]
    int j = i & (NCODES - 1); int c = i >> 14;
    et[i] = emb[j * 64 + c];
    return;
  }
  i -= NCODES * 64;
  if (i < NCODES) {  // e_sq fp32 (ranking only; refine is fp64)
    float s = 0.f;
    for (int c = 0; c < 64; c++) { float v = emb[i * 64 + c]; s += v * v; }
    esq[i] = s; return;
  }
  i -= NCODES;
  if (i < 442368) {  // twt[qi][tap][ci][co] = Wq[qi][co][ci][tap]
    int qi = i / 110592; int r = i % 110592;
    int tap = r >> 12; int ci = (r >> 6) & 63; int co = r & 63;
    twt[i] = Wq[((qi * 64 + co) * 64 + ci) * 27 + tap];
    return;
  }
  i -= 442368;
  if (i < NCODES) { counts[i] = 0; return; }
  i -= NCODES;
  if (i < 4) {
    if (i == 0) *sse = 0.0;
    else if (i == 1) *ent = 0.0;
    else if (i == 2) *usedcnt = 0;
  }
}

// ------------------------------------------- pool (area) + transposed emit
// grid: NSpad blocks (one per output point); 256 thr = 64 ch x 4 win-chunks.
// Lane loads are coalesced across c. Deterministic ((p0+p1)+p2)+p3 combine.
__global__ __launch_bounds__(256) void pool_kernel(
    const float* __restrict__ zcl, const double* __restrict__ accu,
    double* __restrict__ rest64, float* __restrict__ rest32T,
    int N, int NS, int tpn, int pn)
{
  __shared__ double psum[4][64];
  int n = blockIdx.x;
  int tid = threadIdx.x;
  int c = tid & 63, ck = tid >> 6;
  if (n >= N) {  // zero pad columns so argmin reads defined data
    if (tid < 64) rest32T[(size_t)tid * NS + n] = 0.f;
    return;
  }
  int ppn = pn * pn;
  int b = n / (tpn * ppn); int r = n % (tpn * ppn);
  int u = r / ppn; r %= ppn; int v = r / pn; int x = r % pn;
  int t0 = (u * 4) / tpn, t1 = ((u + 1) * 4 + tpn - 1) / tpn;
  int h0 = (v * 16) / pn, h1 = ((v + 1) * 16 + pn - 1) / pn;
  int w0 = (x * 16) / pn, w1 = ((x + 1) * 16 + pn - 1) / pn;
  int nt = t1 - t0, nh = t1 ? (h1 - h0) : 0; nh = h1 - h0; int nw = w1 - w0;
  int M = nt * nh * nw;
  int chunk = (M + 3) >> 2;
  int m0 = ck * chunk; int m1 = m0 + chunk; if (m1 > M) m1 = M;
  double s = 0.0;
  if (m0 < m1) {
    int tmp = m0 / nw; int wi = m0 - tmp * nw;
    int ti = tmp / nh; int hi = tmp - ti * nh;
    for (int m = m0; m < m1; m++) {
      size_t off = (size_t)((((b * 4 + t0 + ti) * 16 + h0 + hi) * 16 + w0 + wi) * 64 + c);
      s += (double)zcl[off] - accu[off];
      if (++wi == nw) { wi = 0; if (++hi == nh) { hi = 0; ++ti; } }
    }
  }
  psum[ck][c] = s;
  __syncthreads();
  if (tid < 64) {
    double t = ((psum[0][c] + psum[1][c]) + psum[2][c]) + psum[3][c];
    // pool-matrix entries are fp32(1/n) used in fp64 (matches np ref)
    float wt = 1.f / (float)nt, wh = 1.f / (float)nh, ww = 1.f / (float)nw;
    double rv = t * (double)wt * (double)wh * (double)ww;
    rest64[(size_t)n * 64 + c] = rv;
    rest32T[(size_t)c * NS + n] = (float)rv;
  }
}

// ------------------------------------------------- argmin pass 1 (fp32 GEMM)
// grid (NS/64, 16): 64 points x 1024-code chunk; 8 tiles of 128 codes.
// Thread = 4p x 8j. Top-2 (value,index) per point with margin for refine.
__global__ __launch_bounds__(256) void argmin_kernel(
    const float* __restrict__ rest32T, const float* __restrict__ et,
    const float* __restrict__ esq, float4* __restrict__ part, int NS)
{
  __shared__ __align__(16) float restT[64][64];   // [k][p]  16 KB
  __shared__ __align__(16) float etile[64][128];  // [k][j]  32 KB
  int tid = threadIdx.x;
  int pbase = blockIdx.x * 64;
  int ch = blockIdx.y;
#pragma unroll
  for (int it = 0; it < 4; it++) {
    int i2 = (tid + it * 256) * 4;
    int k = i2 >> 6, p4 = i2 & 63;
    *(float4*)&restT[k][p4] = *(const float4*)&rest32T[(size_t)k * NS + pbase + p4];
  }
  int tx = tid & 15, ty = tid >> 4;
  float m1[4], m2[4]; int i1[4];
#pragma unroll
  for (int r = 0; r < 4; r++) { m1[r] = 3.4e38f; m2[r] = 3.4e38f; i1[r] = 0x7fffffff; }
  for (int tile = 0; tile < 8; tile++) {
    int j0 = ch * 1024 + tile * 128;
    __syncthreads();
#pragma unroll
    for (int it = 0; it < 8; it++) {
      int i2 = (tid + it * 256) * 4;
      int k = i2 >> 7, jj = i2 & 127;
      *(float4*)&etile[k][jj] = *(const float4*)&et[(size_t)k * NCODES + j0 + jj];
    }
    __syncthreads();
    float acc[4][8];
#pragma unroll
    for (int r = 0; r < 4; r++)
#pragma unroll
      for (int q = 0; q < 8; q++) acc[r][q] = 0.f;
#pragma unroll 8
    for (int k = 0; k < 64; k++) {
      float4 a  = *(const float4*)&restT[k][ty * 4];
      float4 b0 = *(const float4*)&etile[k][tx * 8];
      float4 b1 = *(const float4*)&etile[k][tx * 8 + 4];
      float av[4] = {a.x, a.y, a.z, a.w};
      float bv[8] = {b0.x, b0.y, b0.z, b0.w, b1.x, b1.y, b1.z, b1.w};
#pragma unroll
      for (int r = 0; r < 4; r++)
#pragma unroll
        for (int q = 0; q < 8; q++) acc[r][q] += av[r] * bv[q];
    }
#pragma unroll
    for (int q = 0; q < 8; q++) {
      int j = j0 + tx * 8 + q;
      float es = esq[j];
#pragma unroll
      for (int r = 0; r < 4; r++) {
        float d = es - 2.f * acc[r][q];  // ||z||^2 shift is argmin-invariant
        if (d < m1[r]) { m2[r] = m1[r]; m1[r] = d; i1[r] = j; }
        else if (d < m2[r]) { m2[r] = d; }
      }
    }
  }
  // reduce top-2 across the 16 tx lanes (same wave, same 4 points)
#pragma unroll
  for (int off = 1; off < 16; off <<= 1) {
#pragma unroll
    for (int r = 0; r < 4; r++) {
      float o1 = __shfl_xor(m1[r], off);
      int   oi = __shfl_xor(i1[r], off);
      float o2 = __shfl_xor(m2[r], off);
      bool bwin = (o1 < m1[r]) || (o1 == m1[r] && oi < i1[r]);
      float nm2 = bwin ? fminf(m1[r], o2) : fminf(m2[r], o1);
      if (bwin) { m1[r] = o1; i1[r] = oi; }
      m2[r] = nm2;
    }
  }
  if (tx == 0) {
#pragma unroll
    for (int r = 0; r < 4; r++) {
      int n = pbase + ty * 4 + r;
      part[(size_t)ch * NSP + n] = make_float4(m1[r], m2[r], __int_as_float(i1[r]), 0.f);
    }
  }
}

// -------------------------------- merge chunks + block-local fp64 refine
__global__ __launch_bounds__(256) void reduce_refine_kernel(
    const float4* __restrict__ part, const double* __restrict__ rest64,
    const float* __restrict__ emb, int* __restrict__ idx_cur,
    float* __restrict__ out_idx, int N)
{
  __shared__ int lflag[256];
  __shared__ int lcnt;
  __shared__ double rl[64];
  __shared__ double bm[256];
  __shared__ int    bi[256];
  int tid = threadIdx.x;
  if (tid == 0) lcnt = 0;
  __syncthreads();
  int n = blockIdx.x * 256 + tid;
  if (n < N) {
    float m1 = 3.4e38f, m2 = 3.4e38f; int i1 = 0x7fffffff;
    for (int ch = 0; ch < 16; ch++) {
      float4 q = part[(size_t)ch * NSP + n];
      float o1 = q.x, o2 = q.y; int oi = __float_as_int(q.z);
      bool bwin = (o1 < m1) || (o1 == m1 && oi < i1);
      float nm2 = bwin ? fminf(m1, o2) : fminf(m2, o1);
      if (bwin) { m1 = o1; i1 = oi; }
      m2 = nm2;
    }
    idx_cur[n] = i1;
    out_idx[n] = (float)i1;
    if (m2 - m1 < 0.01f) {  // near-tie: fp32 noise could differ from fp64 ref
      int pos = atomicAdd(&lcnt, 1);
      lflag[pos] = n;
    }
  }
  __syncthreads();
  int cnt = lcnt;
  for (int f = 0; f < cnt; f++) {
    int nn = lflag[f];
    __syncthreads();
    if (tid < 64) rl[tid] = rest64[(size_t)nn * 64 + tid];
    __syncthreads();
    double best = 1e300; int bidx = 0x7fffffff;
    for (int j = tid; j < NCODES; j += 256) {
      double d = 0.0;
      for (int c = 0; c < 64; c++) { double df = rl[c] - (double)emb[(size_t)j * 64 + c]; d += df * df; }
      if (d < best) { best = d; bidx = j; }  // ascending j keeps first min
    }
    bm[tid] = best; bi[tid] = bidx;
    __syncthreads();
    for (int s = 128; s > 0; s >>= 1) {
      if (tid < s) {
        double ob = bm[tid + s]; int oi = bi[tid + s];
        if (ob < bm[tid] || (ob == bm[tid] && oi < bi[tid])) { bm[tid] = ob; bi[tid] = oi; }
      }
      __syncthreads();
    }
    if (tid == 0) { idx_cur[nn] = bi[0]; out_idx[nn] = (float)bi[0]; }
  }
}

// ------------------------------------------------------- trilinear upsample
__device__ inline void axis_map(int L, int outlen, int i, int* j0, int* j1, float* a0, float* a1) {
  if (L == 1) { *j0 = 0; *j1 = 0; *a0 = 1.f; *a1 = 0.f; return; }
  double scale = (double)L / (double)outlen;
  double src = (i + 0.5) * scale - 0.5;
  if (src < 0.0) src = 0.0;
  int i0 = (int)floor(src); if (i0 > L - 1) i0 = L - 1;
  int i1 = i0 + 1; if (i1 > L - 1) i1 = L - 1;
  double wv = src - (double)i0;
  if (i0 == i1) {
    float p = (float)(1.0 - wv), q = (float)wv;  // fp32 += emulation
    *a0 = p + q; *a1 = 0.f;
  } else { *a0 = (float)(1.0 - wv); *a1 = (float)wv; }
  *j0 = i0; *j1 = i1;
}

__global__ __launch_bounds__(256) void upsample_kernel(
    const float* __restrict__ emb, const int* __restrict__ idx_cur,
    double* __restrict__ hup, int tpn, int pn)
{
  int e = blockIdx.x * 256 + threadIdx.x;  // [b][t][h][w][c]
  int c = e & 63, w = (e >> 6) & 15, h = (e >> 10) & 15, t = (e >> 14) & 3, b = e >> 16;
  int t0, t1, h0, h1, w0, w1; float ta0, ta1, ha0, ha1, wa0, wa1;
  axis_map(tpn, 4, t, &t0, &t1, &ta0, &ta1);
  axis_map(pn, 16, h, &h0, &h1, &ha0, &ha1);
  axis_map(pn, 16, w, &w0, &w1, &wa0, &wa1);
  int ti[2] = {t0, t1}; float ta[2] = {ta0, ta1};
  int hi[2] = {h0, h1}; float ha[2] = {ha0, ha1};
  int wi[2] = {w0, w1}; float wa[2] = {wa0, wa1};
  double val = 0.0;
  for (int a = 0; a < 2; a++)
    for (int bb = 0; bb < 2; bb++)
      for (int cc = 0; cc < 2; cc++) {
        double wgt = (double)ta[a] * (double)ha[bb] * (double)wa[cc];
        if (wgt != 0.0) {
          int code = idx_cur[((b * tpn + ti[a]) * pn + hi[bb]) * pn + wi[cc]];
          val += wgt * (double)emb[(size_t)code * 64 + c];
        }
      }
  hup[e] = val;
}

// ------------------------------------------- conv3d + accu update + commit
// grid 256 = b*32 + t*8 + hq ; block: 16 w x 16 co-quads ; 2 h-rows/thread
__global__ __launch_bounds__(256) void conv_kernel(
    const double* __restrict__ hup, const float* __restrict__ twt, const float* __restrict__ bq,
    const float* __restrict__ zcl, double* __restrict__ accu, double* sse, int qi)
{
  __shared__ double hl[3][4][4][18];              // [tt][hh][cc][ww] halo, ci-chunk 4
  __shared__ __align__(16) float wl[27][4][64];   // [tap][cc][co] fp32 (exact)
  __shared__ double red[256];
  int bid = blockIdx.x;
  int b = bid >> 5, t = (bid >> 3) & 3, hq = bid & 7;
  int tid = threadIdx.x;
  int co4 = tid >> 4;  // co = co4*4 .. +3
  int w = tid & 15;
  double acc[2][4];
  for (int k = 0; k < 2; k++) for (int q = 0; q < 4; q++) acc[k][q] = 0.0;
  for (int ci0 = 0; ci0 < 64; ci0 += 4) {
    __syncthreads();
    for (int i = tid; i < 864; i += 256) {
      int ww = i % 18; int r = i / 18; int cc = r & 3; r >>= 2; int hh = r & 3; int tt = r >> 2;
      int gt = t - 1 + tt, gh = hq * 2 - 1 + hh, gw = ww - 1;
      double v = 0.0;
      if (gt >= 0 && gt < 4 && gh >= 0 && gh < 16 && gw >= 0 && gw < 16)
        v = hup[(size_t)((((b * 4 + gt) * 16 + gh) * 16 + gw) * 64 + ci0 + cc)];
      hl[tt][hh][cc][ww] = v;
    }
    for (int i = tid; i < 6912; i += 256) {
      int co = i & 63; int r = i >> 6; int cc = r & 3; int tap = r >> 2;
      wl[tap][cc][co] = twt[(size_t)(((qi * 27 + tap) * 64 + ci0 + cc) * 64 + co)];
    }
    __syncthreads();
    for (int tap = 0; tap < 27; tap++) {
      int dt = tap / 9, dh = (tap / 3) % 3, dw = tap % 3;
#pragma unroll
      for (int cc = 0; cc < 4; cc++) {
        float4 wf = *(const float4*)&wl[tap][cc][co4 * 4];
        double w0 = (double)wf.x, w1 = (double)wf.y, w2 = (double)wf.z, w3 = (double)wf.w;
#pragma unroll
        for (int k = 0; k < 2; k++) {
          double hv = hl[dt][k + dh][cc][w + dw];
          acc[k][0] += hv * w0; acc[k][1] += hv * w1;
          acc[k][2] += hv * w2; acc[k][3] += hv * w3;
        }
      }
    }
  }
  double lsse = 0.0;
  for (int k = 0; k < 2; k++) {
    int gh = hq * 2 + k;
    for (int q = 0; q < 4; q++) {
      int co = co4 * 4 + q;
      size_t off = (size_t)((((b * 4 + t) * 16 + gh) * 16 + w) * 64 + co);
      double conv = acc[k][q] + (double)bq[qi * 64 + co];
      double hu = hup[off];
      double na = accu[off] + 0.5 * hu + 0.5 * conv;  // h*(1-q) + conv*q, q=0.5
      accu[off] = na;
      double df = na - (double)zcl[off];
      lsse += df * df;
    }
  }
  red[tid] = lsse;
  __syncthreads();
  for (int s = 128; s > 0; s >>= 1) { if (tid < s) red[tid] += red[tid + s]; __syncthreads(); }
  if (tid == 0) atomicAdd(sse, red[0]);
}

// ---------------------------------------------------------------- stats
__global__ __launch_bounds__(256) void bincount_kernel(const int* __restrict__ idx_cur, int* counts) {
  int i = blockIdx.x * 256 + threadIdx.x;
  if (i < NSP) atomicAdd(&counts[idx_cur[i]], 1);
}

__global__ __launch_bounds__(256) void stats_kernel(
    const int* __restrict__ counts, float* __restrict__ usage_out, double* ent, int* usedcnt)
{
  __shared__ double re[256];
  __shared__ int ru[256];
  int j = blockIdx.x * 256 + threadIdx.x;
  int cnt = counts[j];
  double p = (double)cnt / 8192.0;
  usage_out[j] = (float)p;
  re[threadIdx.x] = p * log(p + 1e-10);
  ru[threadIdx.x] = cnt > 0 ? 1 : 0;
  __syncthreads();
  for (int s = 128; s > 0; s >>= 1) {
    if (threadIdx.x < s) { re[threadIdx.x] += re[threadIdx.x + s]; ru[threadIdx.x] += ru[threadIdx.x + s]; }
    __syncthreads();
  }
  if (threadIdx.x == 0) { atomicAdd(ent, re[0]); atomicAdd(usedcnt, ru[0]); }
}

__global__ void final_kernel(const double* sse, const double* ent, const int* usedcnt, float* out) {
  if (threadIdx.x == 0) {
    out[NELEM]     = (float)(*sse * 0.25 / 524288.0 / 10.0);
    out[NELEM + 1] = (float)exp(-*ent);
    out[NELEM + 2] = (float)((double)*usedcnt / 16384.0);
  }
}

__global__ __launch_bounds__(256) void embst_kernel(const double* __restrict__ accu, float* __restrict__ out) {
  int e = blockIdx.x * 256 + threadIdx.x;  // out [B,C,T,H,W]
  int w = e & 15, h = (e >> 4) & 15, t = (e >> 8) & 3, c = (e >> 10) & 63, b = e >> 16;
  out[e] = (float)accu[(size_t)(((((b * 4 + t) * 16 + h) * 16 + w) * 64) + c)];
}

// ---------------------------------------------------------------- launch
extern "C" void kernel_launch(void* const* d_in, const int* in_sizes, int n_in,
                              void* d_out, int out_size, void* d_ws, size_t ws_size,
                              hipStream_t stream) {
  static const int T_PN_h[10] = {1, 1, 2, 2, 2, 4, 4, 4, 4, 4};
  static const int V_PN_h[10] = {1, 2, 3, 4, 5, 6, 8, 10, 13, 16};
  // qi from bit-exact fp64 emulation of np.linspace+argmin (ties: si=2->1, si=7->3)
  static const int QI_h[10]   = {0, 0, 1, 1, 1, 2, 2, 3, 3, 3};
  static const int NS_h[10]   = {8, 32, 144, 256, 400, 1152, 2048, 3200, 5408, 8192};
  static const int OB_h[10]   = {540675, 540683, 540715, 540859, 541115,
                                 541515, 542667, 544715, 547915, 553323};

  const float* z   = (const float*)d_in[0];
  const float* emb = (const float*)d_in[1];
  const float* Wq  = (const float*)d_in[2];
  const float* bq  = (const float*)d_in[3];
  float* out = (float*)d_out;
  char* ws = (char*)d_ws;

  double* accu    = (double*)(ws + WS_ACCU);
  double* hup     = (double*)(ws + WS_HUP);
  double* rest64  = (double*)(ws + WS_REST64);
  float4* part    = (float4*)(ws + WS_PART);
  float*  zcl     = (float*)(ws + WS_ZCL);
  float*  et      = (float*)(ws + WS_ET);
  float*  esq     = (float*)(ws + WS_ESQ);
  float*  twt     = (float*)(ws + WS_TWT);
  int*    idx_cur = (int*)(ws + WS_IDX);
  int*    counts  = (int*)(ws + WS_CNT);
  double* sse     = (double*)(ws + WS_SSE);
  double* ent     = (double*)(ws + WS_ENT);
  int*    usedcnt = (int*)(ws + WS_USED);
  float*  rest32T = (float*)(ws + WS_R32T);

  prep_kernel<<<10049, 256, 0, stream>>>(z, emb, Wq, accu, zcl, et, esq, twt,
                                         counts, sse, ent, usedcnt);

  for (int si = 0; si < 10; si++) {
    int tpn = T_PN_h[si], pn = V_PN_h[si], N = NS_h[si];
    int NSpad = (N + 63) & ~63;
    pool_kernel<<<NSpad, 256, 0, stream>>>(zcl, accu, rest64, rest32T, N, NSpad, tpn, pn);
    dim3 ag(NSpad / 64, 16);
    argmin_kernel<<<ag, 256, 0, stream>>>(rest32T, et, esq, part, NSpad);
    reduce_refine_kernel<<<(N + 255) / 256, 256, 0, stream>>>(part, rest64, emb, idx_cur,
                                                              out + OB_h[si], N);
    upsample_kernel<<<NELEM / 256, 256, 0, stream>>>(emb, idx_cur, hup, tpn, pn);
    conv_kernel<<<256, 256, 0, stream>>>(hup, twt, bq, zcl, accu, sse, QI_h[si]);
  }

  bincount_kernel<<<32, 256, 0, stream>>>(idx_cur, counts);
  stats_kernel<<<64, 256, 0, stream>>>(counts, out + 524291, ent, usedcnt);
  final_kernel<<<1, 64, 0, stream>>>(sse, ent, usedcnt, out);
  embst_kernel<<<NELEM / 256, 256, 0, stream>>>(accu, out);
}

// Round 5
// 3371.877 us; speedup vs baseline: 2.2078x; 1.6240x over previous
//
#include <hip/hip_runtime.h>
#include <math.h>

// MultiScaleCodebook on MI355X — round 5: parallel fp64 refine.
// r4 post-mortem: reduce_refine ~505us x10 = whole runtime; refine loop was
// serial over flagged points within <=32 blocks (1 block at small scales),
// each rescan streaming 4MB codebook from one CU. Fix: global flag list ->
// refine grid (N,4) one block per (flag, 4096-code chunk) -> tiny merge.
// Numerics unchanged: fp64 chain, fp32 pass-1 with 0.01 top-2 margin,
// fp64 full rescan of flagged points, same tie rules (first min).

#define NCODES 16384
#define NELEM  524288   // 8*64*4*16*16
#define NSP    8192     // 8*4*16*16

// workspace byte offsets (total ~27.1 MB)
#define WS_ACCU   0ul
#define WS_HUP    4194304ul
#define WS_REST64 8388608ul
#define WS_PART   12582912ul   // 2MB; refine pbest aliases this (stream-ordered)
#define WS_ZCL    16777216ul
#define WS_ET     18874368ul
#define WS_ESQ    23068672ul
#define WS_TWT    23134208ul
#define WS_IDX    24903680ul
#define WS_CNT    24936448ul
#define WS_FLAGL  25001984ul   // 8192 ints
#define WS_FLAGC  25034752ul   // 10 ints (per-scale counters)
#define WS_SSE    25034816ul
#define WS_ENT    25034824ul
#define WS_USED   25034832ul
#define WS_R32T   25034848ul   // rest32T [64][NSpad] fp32, <= 2 MB

struct PBest { double d; int idx; int pad; };

// ---------------------------------------------------------------- prep
__global__ __launch_bounds__(256) void prep_kernel(
    const float* __restrict__ z, const float* __restrict__ emb, const float* __restrict__ Wq,
    double* __restrict__ accu, float* __restrict__ zcl, float* __restrict__ et,
    float* __restrict__ esq, float* __restrict__ twt,
    int* __restrict__ counts, int* __restrict__ flagcnt,
    double* sse, double* ent, int* usedcnt)
{
  int i = blockIdx.x * 256 + threadIdx.x;
  if (i < NELEM) { accu[i] = 0.0; return; }
  i -= NELEM;
  if (i < NELEM) {  // z [B,C,T,H,W] -> zcl [B,T,H,W,C]
    int c = i & 63, w = (i >> 6) & 15, h = (i >> 10) & 15, t = (i >> 14) & 3, b = i >> 16;
    zcl[i] = z[(((b * 64 + c) * 4 + t) * 16 + h) * 16 + w];
    return;
  }
  i -= NELEM;
  if (i < NCODES * 64) {  // et[c][j] = emb[j][c]
    int j = i & (NCODES - 1); int c = i >> 14;
    et[i] = emb[j * 64 + c];
    return;
  }
  i -= NCODES * 64;
  if (i < NCODES) {  // e_sq fp32 (ranking only; refine is fp64)
    float s = 0.f;
    for (int c = 0; c < 64; c++) { float v = emb[i * 64 + c]; s += v * v; }
    esq[i] = s; return;
  }
  i -= NCODES;
  if (i < 442368) {  // twt[qi][tap][ci][co] = Wq[qi][co][ci][tap]
    int qi = i / 110592; int r = i % 110592;
    int tap = r >> 12; int ci = (r >> 6) & 63; int co = r & 63;
    twt[i] = Wq[((qi * 64 + co) * 64 + ci) * 27 + tap];
    return;
  }
  i -= 442368;
  if (i < NCODES) { counts[i] = 0; return; }
  i -= NCODES;
  if (i < 16) {
    if (i < 10) flagcnt[i] = 0;
    else if (i == 10) *sse = 0.0;
    else if (i == 11) *ent = 0.0;
    else if (i == 12) *usedcnt = 0;
  }
}

// ------------------------------------------- pool (area) + transposed emit
// grid: NSpad blocks (one per output point); 256 thr = 64 ch x 4 win-chunks.
__global__ __launch_bounds__(256) void pool_kernel(
    const float* __restrict__ zcl, const double* __restrict__ accu,
    double* __restrict__ rest64, float* __restrict__ rest32T,
    int N, int NS, int tpn, int pn)
{
  __shared__ double psum[4][64];
  int n = blockIdx.x;
  int tid = threadIdx.x;
  int c = tid & 63, ck = tid >> 6;
  if (n >= N) {  // zero pad columns so argmin reads defined data
    if (tid < 64) rest32T[(size_t)tid * NS + n] = 0.f;
    return;
  }
  int ppn = pn * pn;
  int b = n / (tpn * ppn); int r = n % (tpn * ppn);
  int u = r / ppn; r %= ppn; int v = r / pn; int x = r % pn;
  int t0 = (u * 4) / tpn, t1 = ((u + 1) * 4 + tpn - 1) / tpn;
  int h0 = (v * 16) / pn, h1 = ((v + 1) * 16 + pn - 1) / pn;
  int w0 = (x * 16) / pn, w1 = ((x + 1) * 16 + pn - 1) / pn;
  int nt = t1 - t0, nh = h1 - h0, nw = w1 - w0;
  int M = nt * nh * nw;
  int chunk = (M + 3) >> 2;
  int m0 = ck * chunk; int m1 = m0 + chunk; if (m1 > M) m1 = M;
  double s = 0.0;
  if (m0 < m1) {
    int tmp = m0 / nw; int wi = m0 - tmp * nw;
    int ti = tmp / nh; int hi = tmp - ti * nh;
    for (int m = m0; m < m1; m++) {
      size_t off = (size_t)((((b * 4 + t0 + ti) * 16 + h0 + hi) * 16 + w0 + wi) * 64 + c);
      s += (double)zcl[off] - accu[off];
      if (++wi == nw) { wi = 0; if (++hi == nh) { hi = 0; ++ti; } }
    }
  }
  psum[ck][c] = s;
  __syncthreads();
  if (tid < 64) {
    double t = ((psum[0][c] + psum[1][c]) + psum[2][c]) + psum[3][c];
    // pool-matrix entries are fp32(1/n) used in fp64 (matches np ref)
    float wt = 1.f / (float)nt, wh = 1.f / (float)nh, ww = 1.f / (float)nw;
    double rv = t * (double)wt * (double)wh * (double)ww;
    rest64[(size_t)n * 64 + c] = rv;
    rest32T[(size_t)c * NS + n] = (float)rv;
  }
}

// ------------------------------------------------- argmin pass 1 (fp32 GEMM)
// grid (NS/64, 16): 64 points x 1024-code chunk; 8 tiles of 128 codes.
__global__ __launch_bounds__(256) void argmin_kernel(
    const float* __restrict__ rest32T, const float* __restrict__ et,
    const float* __restrict__ esq, float4* __restrict__ part, int NS)
{
  __shared__ __align__(16) float restT[64][64];   // [k][p]  16 KB
  __shared__ __align__(16) float etile[64][128];  // [k][j]  32 KB
  int tid = threadIdx.x;
  int pbase = blockIdx.x * 64;
  int ch = blockIdx.y;
#pragma unroll
  for (int it = 0; it < 4; it++) {
    int i2 = (tid + it * 256) * 4;
    int k = i2 >> 6, p4 = i2 & 63;
    *(float4*)&restT[k][p4] = *(const float4*)&rest32T[(size_t)k * NS + pbase + p4];
  }
  int tx = tid & 15, ty = tid >> 4;
  float m1[4], m2[4]; int i1[4];
#pragma unroll
  for (int r = 0; r < 4; r++) { m1[r] = 3.4e38f; m2[r] = 3.4e38f; i1[r] = 0x7fffffff; }
  for (int tile = 0; tile < 8; tile++) {
    int j0 = ch * 1024 + tile * 128;
    __syncthreads();
#pragma unroll
    for (int it = 0; it < 8; it++) {
      int i2 = (tid + it * 256) * 4;
      int k = i2 >> 7, jj = i2 & 127;
      *(float4*)&etile[k][jj] = *(const float4*)&et[(size_t)k * NCODES + j0 + jj];
    }
    __syncthreads();
    float acc[4][8];
#pragma unroll
    for (int r = 0; r < 4; r++)
#pragma unroll
      for (int q = 0; q < 8; q++) acc[r][q] = 0.f;
#pragma unroll 8
    for (int k = 0; k < 64; k++) {
      float4 a  = *(const float4*)&restT[k][ty * 4];
      float4 b0 = *(const float4*)&etile[k][tx * 8];
      float4 b1 = *(const float4*)&etile[k][tx * 8 + 4];
      float av[4] = {a.x, a.y, a.z, a.w};
      float bv[8] = {b0.x, b0.y, b0.z, b0.w, b1.x, b1.y, b1.z, b1.w};
#pragma unroll
      for (int r = 0; r < 4; r++)
#pragma unroll
        for (int q = 0; q < 8; q++) acc[r][q] += av[r] * bv[q];
    }
#pragma unroll
    for (int q = 0; q < 8; q++) {
      int j = j0 + tx * 8 + q;
      float es = esq[j];
#pragma unroll
      for (int r = 0; r < 4; r++) {
        float d = es - 2.f * acc[r][q];  // ||z||^2 shift is argmin-invariant
        if (d < m1[r]) { m2[r] = m1[r]; m1[r] = d; i1[r] = j; }
        else if (d < m2[r]) { m2[r] = d; }
      }
    }
  }
#pragma unroll
  for (int off = 1; off < 16; off <<= 1) {
#pragma unroll
    for (int r = 0; r < 4; r++) {
      float o1 = __shfl_xor(m1[r], off);
      int   oi = __shfl_xor(i1[r], off);
      float o2 = __shfl_xor(m2[r], off);
      bool bwin = (o1 < m1[r]) || (o1 == m1[r] && oi < i1[r]);
      float nm2 = bwin ? fminf(m1[r], o2) : fminf(m2[r], o1);
      if (bwin) { m1[r] = o1; i1[r] = oi; }
      m2[r] = nm2;
    }
  }
  if (tx == 0) {
#pragma unroll
    for (int r = 0; r < 4; r++) {
      int n = pbase + ty * 4 + r;
      part[(size_t)ch * NSP + n] = make_float4(m1[r], m2[r], __int_as_float(i1[r]), 0.f);
    }
  }
}

// ---------------------------- merge chunks, flag near-ties to global list
__global__ __launch_bounds__(256) void reduce_kernel(
    const float4* __restrict__ part, int* __restrict__ idx_cur,
    float* __restrict__ out_idx, int* flagcnt, int* flaglist, int N)
{
  int n = blockIdx.x * 256 + threadIdx.x;
  if (n >= N) return;
  float m1 = 3.4e38f, m2 = 3.4e38f; int i1 = 0x7fffffff;
  for (int ch = 0; ch < 16; ch++) {
    float4 q = part[(size_t)ch * NSP + n];
    float o1 = q.x, o2 = q.y; int oi = __float_as_int(q.z);
    bool bwin = (o1 < m1) || (o1 == m1 && oi < i1);
    float nm2 = bwin ? fminf(m1, o2) : fminf(m2, o1);
    if (bwin) { m1 = o1; i1 = oi; }
    m2 = nm2;
  }
  idx_cur[n] = i1;
  out_idx[n] = (float)i1;
  if (m2 - m1 < 0.01f) {  // near-tie: fp32 noise could differ from fp64 ref
    int pos = atomicAdd(flagcnt, 1);   // <= N by construction
    flaglist[pos] = n;
  }
}

// -------------------- parallel fp64 rescan: block = (flag, 4096-code chunk)
__global__ __launch_bounds__(256) void refine_kernel(
    const double* __restrict__ rest64, const float* __restrict__ emb,
    const int* __restrict__ flagcnt, const int* __restrict__ flaglist,
    PBest* __restrict__ pbest)
{
  __shared__ double rl[64];
  __shared__ double bm[256];
  __shared__ int    bi[256];
  int f = blockIdx.x;
  if (f >= *flagcnt) return;
  int ch = blockIdx.y;
  int tid = threadIdx.x;
  int n = flaglist[f];
  if (tid < 64) rl[tid] = rest64[(size_t)n * 64 + tid];
  __syncthreads();
  double best = 1e300; int bidx = 0x7fffffff;
  for (int k = 0; k < 16; k++) {
    int j = ch * 4096 + k * 256 + tid;
    double d = 0.0;
    for (int c = 0; c < 64; c++) { double df = rl[c] - (double)emb[(size_t)j * 64 + c]; d += df * df; }
    if (d < best) { best = d; bidx = j; }  // ascending j keeps first min
  }
  bm[tid] = best; bi[tid] = bidx;
  __syncthreads();
  for (int s = 128; s > 0; s >>= 1) {
    if (tid < s) {
      double ob = bm[tid + s]; int oi = bi[tid + s];
      if (ob < bm[tid] || (ob == bm[tid] && oi < bi[tid])) { bm[tid] = ob; bi[tid] = oi; }
    }
    __syncthreads();
  }
  if (tid == 0) { pbest[f * 4 + ch].d = bm[0]; pbest[f * 4 + ch].idx = bi[0]; }
}

// -------------------------------- fold 4 chunk results per flagged point
__global__ __launch_bounds__(256) void refine_merge_kernel(
    const PBest* __restrict__ pbest, const int* __restrict__ flagcnt,
    const int* __restrict__ flaglist, int* __restrict__ idx_cur,
    float* __restrict__ out_idx)
{
  int f = blockIdx.x * 256 + threadIdx.x;
  if (f >= *flagcnt) return;
  double best = 1e300; int bidx = 0x7fffffff;
  for (int ch = 0; ch < 4; ch++) {  // ascending chunk keeps first min
    double d = pbest[f * 4 + ch].d; int j = pbest[f * 4 + ch].idx;
    if (d < best || (d == best && j < bidx)) { best = d; bidx = j; }
  }
  int n = flaglist[f];
  idx_cur[n] = bidx;
  out_idx[n] = (float)bidx;
}

// ------------------------------------------------------- trilinear upsample
__device__ inline void axis_map(int L, int outlen, int i, int* j0, int* j1, float* a0, float* a1) {
  if (L == 1) { *j0 = 0; *j1 = 0; *a0 = 1.f; *a1 = 0.f; return; }
  double scale = (double)L / (double)outlen;
  double src = (i + 0.5) * scale - 0.5;
  if (src < 0.0) src = 0.0;
  int i0 = (int)floor(src); if (i0 > L - 1) i0 = L - 1;
  int i1 = i0 + 1; if (i1 > L - 1) i1 = L - 1;
  double wv = src - (double)i0;
  if (i0 == i1) {
    float p = (float)(1.0 - wv), q = (float)wv;  // fp32 += emulation
    *a0 = p + q; *a1 = 0.f;
  } else { *a0 = (float)(1.0 - wv); *a1 = (float)wv; }
  *j0 = i0; *j1 = i1;
}

__global__ __launch_bounds__(256) void upsample_kernel(
    const float* __restrict__ emb, const int* __restrict__ idx_cur,
    double* __restrict__ hup, int tpn, int pn)
{
  int e = blockIdx.x * 256 + threadIdx.x;  // [b][t][h][w][c]
  int c = e & 63, w = (e >> 6) & 15, h = (e >> 10) & 15, t = (e >> 14) & 3, b = e >> 16;
  int t0, t1, h0, h1, w0, w1; float ta0, ta1, ha0, ha1, wa0, wa1;
  axis_map(tpn, 4, t, &t0, &t1, &ta0, &ta1);
  axis_map(pn, 16, h, &h0, &h1, &ha0, &ha1);
  axis_map(pn, 16, w, &w0, &w1, &wa0, &wa1);
  int ti[2] = {t0, t1}; float ta[2] = {ta0, ta1};
  int hi[2] = {h0, h1}; float ha[2] = {ha0, ha1};
  int wi[2] = {w0, w1}; float wa[2] = {wa0, wa1};
  double val = 0.0;
  for (int a = 0; a < 2; a++)
    for (int bb = 0; bb < 2; bb++)
      for (int cc = 0; cc < 2; cc++) {
        double wgt = (double)ta[a] * (double)ha[bb] * (double)wa[cc];
        if (wgt != 0.0) {
          int code = idx_cur[((b * tpn + ti[a]) * pn + hi[bb]) * pn + wi[cc]];
          val += wgt * (double)emb[(size_t)code * 64 + c];
        }
      }
  hup[e] = val;
}

// ------------------------------------------- conv3d + accu update + commit
__global__ __launch_bounds__(256) void conv_kernel(
    const double* __restrict__ hup, const float* __restrict__ twt, const float* __restrict__ bq,
    const float* __restrict__ zcl, double* __restrict__ accu, double* sse, int qi)
{
  __shared__ double hl[3][4][4][18];              // [tt][hh][cc][ww] halo, ci-chunk 4
  __shared__ __align__(16) float wl[27][4][64];   // [tap][cc][co] fp32 (exact)
  __shared__ double red[256];
  int bid = blockIdx.x;
  int b = bid >> 5, t = (bid >> 3) & 3, hq = bid & 7;
  int tid = threadIdx.x;
  int co4 = tid >> 4;  // co = co4*4 .. +3
  int w = tid & 15;
  double acc[2][4];
  for (int k = 0; k < 2; k++) for (int q = 0; q < 4; q++) acc[k][q] = 0.0;
  for (int ci0 = 0; ci0 < 64; ci0 += 4) {
    __syncthreads();
    for (int i = tid; i < 864; i += 256) {
      int ww = i % 18; int r = i / 18; int cc = r & 3; r >>= 2; int hh = r & 3; int tt = r >> 2;
      int gt = t - 1 + tt, gh = hq * 2 - 1 + hh, gw = ww - 1;
      double v = 0.0;
      if (gt >= 0 && gt < 4 && gh >= 0 && gh < 16 && gw >= 0 && gw < 16)
        v = hup[(size_t)((((b * 4 + gt) * 16 + gh) * 16 + gw) * 64 + ci0 + cc)];
      hl[tt][hh][cc][ww] = v;
    }
    for (int i = tid; i < 6912; i += 256) {
      int co = i & 63; int r = i >> 6; int cc = r & 3; int tap = r >> 2;
      wl[tap][cc][co] = twt[(size_t)(((qi * 27 + tap) * 64 + ci0 + cc) * 64 + co)];
    }
    __syncthreads();
    for (int tap = 0; tap < 27; tap++) {
      int dt = tap / 9, dh = (tap / 3) % 3, dw = tap % 3;
#pragma unroll
      for (int cc = 0; cc < 4; cc++) {
        float4 wf = *(const float4*)&wl[tap][cc][co4 * 4];
        double w0 = (double)wf.x, w1 = (double)wf.y, w2 = (double)wf.z, w3 = (double)wf.w;
#pragma unroll
        for (int k = 0; k < 2; k++) {
          double hv = hl[dt][k + dh][cc][w + dw];
          acc[k][0] += hv * w0; acc[k][1] += hv * w1;
          acc[k][2] += hv * w2; acc[k][3] += hv * w3;
        }
      }
    }
  }
  double lsse = 0.0;
  for (int k = 0; k < 2; k++) {
    int gh = hq * 2 + k;
    for (int q = 0; q < 4; q++) {
      int co = co4 * 4 + q;
      size_t off = (size_t)((((b * 4 + t) * 16 + gh) * 16 + w) * 64 + co);
      double conv = acc[k][q] + (double)bq[qi * 64 + co];
      double hu = hup[off];
      double na = accu[off] + 0.5 * hu + 0.5 * conv;  // h*(1-q) + conv*q, q=0.5
      accu[off] = na;
      double df = na - (double)zcl[off];
      lsse += df * df;
    }
  }
  red[tid] = lsse;
  __syncthreads();
  for (int s = 128; s > 0; s >>= 1) { if (tid < s) red[tid] += red[tid + s]; __syncthreads(); }
  if (tid == 0) atomicAdd(sse, red[0]);
}

// ---------------------------------------------------------------- stats
__global__ __launch_bounds__(256) void bincount_kernel(const int* __restrict__ idx_cur, int* counts) {
  int i = blockIdx.x * 256 + threadIdx.x;
  if (i < NSP) atomicAdd(&counts[idx_cur[i]], 1);
}

__global__ __launch_bounds__(256) void stats_kernel(
    const int* __restrict__ counts, float* __restrict__ usage_out, double* ent, int* usedcnt)
{
  __shared__ double re[256];
  __shared__ int ru[256];
  int j = blockIdx.x * 256 + threadIdx.x;
  int cnt = counts[j];
  double p = (double)cnt / 8192.0;
  usage_out[j] = (float)p;
  re[threadIdx.x] = p * log(p + 1e-10);
  ru[threadIdx.x] = cnt > 0 ? 1 : 0;
  __syncthreads();
  for (int s = 128; s > 0; s >>= 1) {
    if (threadIdx.x < s) { re[threadIdx.x] += re[threadIdx.x + s]; ru[threadIdx.x] += ru[threadIdx.x + s]; }
    __syncthreads();
  }
  if (threadIdx.x == 0) { atomicAdd(ent, re[0]); atomicAdd(usedcnt, ru[0]); }
}

__global__ void final_kernel(const double* sse, const double* ent, const int* usedcnt, float* out) {
  if (threadIdx.x == 0) {
    out[NELEM]     = (float)(*sse * 0.25 / 524288.0 / 10.0);
    out[NELEM + 1] = (float)exp(-*ent);
    out[NELEM + 2] = (float)((double)*usedcnt / 16384.0);
  }
}

__global__ __launch_bounds__(256) void embst_kernel(const double* __restrict__ accu, float* __restrict__ out) {
  int e = blockIdx.x * 256 + threadIdx.x;  // out [B,C,T,H,W]
  int w = e & 15, h = (e >> 4) & 15, t = (e >> 8) & 3, c = (e >> 10) & 63, b = e >> 16;
  out[e] = (float)accu[(size_t)(((((b * 4 + t) * 16 + h) * 16 + w) * 64) + c)];
}

// ---------------------------------------------------------------- launch
extern "C" void kernel_launch(void* const* d_in, const int* in_sizes, int n_in,
                              void* d_out, int out_size, void* d_ws, size_t ws_size,
                              hipStream_t stream) {
  static const int T_PN_h[10] = {1, 1, 2, 2, 2, 4, 4, 4, 4, 4};
  static const int V_PN_h[10] = {1, 2, 3, 4, 5, 6, 8, 10, 13, 16};
  // qi from bit-exact fp64 emulation of np.linspace+argmin (ties: si=2->1, si=7->3)
  static const int QI_h[10]   = {0, 0, 1, 1, 1, 2, 2, 3, 3, 3};
  static const int NS_h[10]   = {8, 32, 144, 256, 400, 1152, 2048, 3200, 5408, 8192};
  static const int OB_h[10]   = {540675, 540683, 540715, 540859, 541115,
                                 541515, 542667, 544715, 547915, 553323};

  const float* z   = (const float*)d_in[0];
  const float* emb = (const float*)d_in[1];
  const float* Wq  = (const float*)d_in[2];
  const float* bq  = (const float*)d_in[3];
  float* out = (float*)d_out;
  char* ws = (char*)d_ws;

  double* accu    = (double*)(ws + WS_ACCU);
  double* hup     = (double*)(ws + WS_HUP);
  double* rest64  = (double*)(ws + WS_REST64);
  float4* part    = (float4*)(ws + WS_PART);
  PBest*  pbest   = (PBest*)(ws + WS_PART);   // alias: part dead when pbest written
  float*  zcl     = (float*)(ws + WS_ZCL);
  float*  et      = (float*)(ws + WS_ET);
  float*  esq     = (float*)(ws + WS_ESQ);
  float*  twt     = (float*)(ws + WS_TWT);
  int*    idx_cur = (int*)(ws + WS_IDX);
  int*    counts  = (int*)(ws + WS_CNT);
  int*    flaglist= (int*)(ws + WS_FLAGL);
  int*    flagcnt = (int*)(ws + WS_FLAGC);
  double* sse     = (double*)(ws + WS_SSE);
  double* ent     = (double*)(ws + WS_ENT);
  int*    usedcnt = (int*)(ws + WS_USED);
  float*  rest32T = (float*)(ws + WS_R32T);

  prep_kernel<<<10049, 256, 0, stream>>>(z, emb, Wq, accu, zcl, et, esq, twt,
                                         counts, flagcnt, sse, ent, usedcnt);

  for (int si = 0; si < 10; si++) {
    int tpn = T_PN_h[si], pn = V_PN_h[si], N = NS_h[si];
    int NSpad = (N + 63) & ~63;
    pool_kernel<<<NSpad, 256, 0, stream>>>(zcl, accu, rest64, rest32T, N, NSpad, tpn, pn);
    dim3 ag(NSpad / 64, 16);
    argmin_kernel<<<ag, 256, 0, stream>>>(rest32T, et, esq, part, NSpad);
    reduce_kernel<<<(N + 255) / 256, 256, 0, stream>>>(part, idx_cur, out + OB_h[si],
                                                       flagcnt + si, flaglist, N);
    dim3 rg(N, 4);   // flags <= N; idle blocks exit on flagcnt read
    refine_kernel<<<rg, 256, 0, stream>>>(rest64, emb, flagcnt + si, flaglist, pbest);
    refine_merge_kernel<<<(N + 255) / 256, 256, 0, stream>>>(pbest, flagcnt + si, flaglist,
                                                             idx_cur, out + OB_h[si]);
    upsample_kernel<<<NELEM / 256, 256, 0, stream>>>(emb, idx_cur, hup, tpn, pn);
    conv_kernel<<<256, 256, 0, stream>>>(hup, twt, bq, zcl, accu, sse, QI_h[si]);
  }

  bincount_kernel<<<32, 256, 0, stream>>>(idx_cur, counts);
  stats_kernel<<<64, 256, 0, stream>>>(counts, out + 524291, ent, usedcnt);
  final_kernel<<<1, 64, 0, stream>>>(sse, ent, usedcnt, out);
  embst_kernel<<<NELEM / 256, 256, 0, stream>>>(accu, out);
}

// Round 6
// 2623.138 us; speedup vs baseline: 2.8380x; 1.2854x over previous
//
#include <hip/hip_runtime.h>
#include <math.h>

// MultiScaleCodebook on MI355X — round 6: MFMA argmin (split-bf16).
// r5 post-mortem: argmin VALU-bound (fp32 GEMM floor 278us on vector pipe)
// + 3.35e7 LDS conflicts from etile[tx*8] 4-way reads. Fix: move the GEMM
// to matrix cores: dot = rh*eh + rh*el + rl*eh (3x mfma_f32_16x16x32_bf16,
// error ~7e-4 << 0.01 refine margin). rest/emb stored frag-preordered in
// global so LDS staging is a linear conflict-free copy. fp64 chain, margin
// flags, fp64 refine unchanged -> pass-1 precision cannot flip outputs.

#define NCODES 16384
#define NELEM  524288   // 8*64*4*16*16
#define NSP    8192     // 8*4*16*16

// workspace byte offsets (total ~27.1 MB)
#define WS_ACCU   0ul
#define WS_HUP    4194304ul
#define WS_REST64 8388608ul
#define WS_PART   12582912ul   // 2MB; refine pbest aliases this
#define WS_ZCL    16777216ul
#define WS_EHF    18874368ul   // emb bf16-hi frags, 2MB
#define WS_ELF    20971520ul   // emb bf16-lo frags, 2MB
#define WS_ESQ    23068672ul
#define WS_TWT    23134208ul
#define WS_IDX    24903680ul
#define WS_CNT    24936448ul
#define WS_FLAGL  25001984ul
#define WS_FLAGC  25034752ul
#define WS_SSE    25034816ul
#define WS_ENT    25034824ul
#define WS_USED   25034832ul
#define WS_RHF    25034848ul   // rest bf16-hi frags, 1MB
#define WS_RLF    26083424ul   // rest bf16-lo frags, 1MB

typedef __attribute__((ext_vector_type(8))) short short8;
typedef __attribute__((ext_vector_type(4))) float floatx4;

struct PBest { double d; int idx; int pad; };

// round-to-nearest-even float -> bf16; also returns hi as float
__device__ inline short bf16rne(float f, float* hi) {
  unsigned u = __float_as_uint(f);
  unsigned r = (u + 0x7FFFu + ((u >> 16) & 1u)) >> 16;
  *hi = __uint_as_float(r << 16);
  return (short)r;
}

// ---------------------------------------------------------------- prep
__global__ __launch_bounds__(256) void prep_kernel(
    const float* __restrict__ z, const float* __restrict__ emb, const float* __restrict__ Wq,
    double* __restrict__ accu, float* __restrict__ zcl,
    short* __restrict__ ehf, short* __restrict__ elf,
    float* __restrict__ esq, float* __restrict__ twt,
    int* __restrict__ counts, int* __restrict__ flagcnt,
    double* sse, double* ent, int* usedcnt)
{
  int i = blockIdx.x * 256 + threadIdx.x;
  if (i < NELEM) { accu[i] = 0.0; return; }
  i -= NELEM;
  if (i < NELEM) {  // z [B,C,T,H,W] -> zcl [B,T,H,W,C]
    int c = i & 63, w = (i >> 6) & 15, h = (i >> 10) & 15, t = (i >> 14) & 3, b = i >> 16;
    zcl[i] = z[(((b * 64 + c) * 4 + t) * 16 + h) * 16 + w];
    return;
  }
  i -= NELEM;
  if (i < NCODES * 64) {  // emb -> bf16 split, MFMA B-frag order
    int j = i >> 6, c = i & 63;
    float v = emb[i];
    float hi; short h = bf16rne(v, &hi);
    float hi2; short l = bf16rne(v - hi, &hi2);
    int jt = j >> 4, nn = j & 15, hf = c >> 5, q = (c >> 3) & 3, ii = c & 7;
    size_t slot = ((size_t)(((jt * 2 + hf) * 64) + q * 16 + nn)) * 8 + ii;
    ehf[slot] = h; elf[slot] = l;
    return;
  }
  i -= NCODES * 64;
  if (i < NCODES) {  // e_sq fp32 (ranking only; refine is fp64)
    float s = 0.f;
    for (int c = 0; c < 64; c++) { float v = emb[i * 64 + c]; s += v * v; }
    esq[i] = s; return;
  }
  i -= NCODES;
  if (i < 442368) {  // twt[qi][tap][ci][co] = Wq[qi][co][ci][tap]
    int qi = i / 110592; int r = i % 110592;
    int tap = r >> 12; int ci = (r >> 6) & 63; int co = r & 63;
    twt[i] = Wq[((qi * 64 + co) * 64 + ci) * 27 + tap];
    return;
  }
  i -= 442368;
  if (i < NCODES) { counts[i] = 0; return; }
  i -= NCODES;
  if (i < 16) {
    if (i < 10) flagcnt[i] = 0;
    else if (i == 10) *sse = 0.0;
    else if (i == 11) *ent = 0.0;
    else if (i == 12) *usedcnt = 0;
  }
}

// ------------------------------------------- pool (area) + frag emit
// grid: NSpad blocks (one per output point); 256 thr = 64 ch x 4 win-chunks.
__global__ __launch_bounds__(256) void pool_kernel(
    const float* __restrict__ zcl, const double* __restrict__ accu,
    double* __restrict__ rest64, short* __restrict__ rhf, short* __restrict__ rlf,
    int N, int tpn, int pn)
{
  __shared__ double psum[4][64];
  int n = blockIdx.x;
  int tid = threadIdx.x;
  int c = tid & 63, ck = tid >> 6;
  if (n >= N) {  // zero pad rows so argmin frags are defined
    if (tid < 64) {
      int pt = n >> 4, m = n & 15, hf = tid >> 5, q = (tid >> 3) & 3, ii = tid & 7;
      size_t slot = ((size_t)(((pt * 2 + hf) * 64) + q * 16 + m)) * 8 + ii;
      rhf[slot] = 0; rlf[slot] = 0;
    }
    return;
  }
  int ppn = pn * pn;
  int b = n / (tpn * ppn); int r = n % (tpn * ppn);
  int u = r / ppn; r %= ppn; int v = r / pn; int x = r % pn;
  int t0 = (u * 4) / tpn, t1 = ((u + 1) * 4 + tpn - 1) / tpn;
  int h0 = (v * 16) / pn, h1 = ((v + 1) * 16 + pn - 1) / pn;
  int w0 = (x * 16) / pn, w1 = ((x + 1) * 16 + pn - 1) / pn;
  int nt = t1 - t0, nh = h1 - h0, nw = w1 - w0;
  int M = nt * nh * nw;
  int chunk = (M + 3) >> 2;
  int m0 = ck * chunk; int m1 = m0 + chunk; if (m1 > M) m1 = M;
  double s = 0.0;
  if (m0 < m1) {
    int tmp = m0 / nw; int wi = m0 - tmp * nw;
    int ti = tmp / nh; int hi = tmp - ti * nh;
    for (int m = m0; m < m1; m++) {
      size_t off = (size_t)((((b * 4 + t0 + ti) * 16 + h0 + hi) * 16 + w0 + wi) * 64 + c);
      s += (double)zcl[off] - accu[off];
      if (++wi == nw) { wi = 0; if (++hi == nh) { hi = 0; ++ti; } }
    }
  }
  psum[ck][c] = s;
  __syncthreads();
  if (tid < 64) {
    double t = ((psum[0][c] + psum[1][c]) + psum[2][c]) + psum[3][c];
    // pool-matrix entries are fp32(1/n) used in fp64 (matches np ref)
    float wt = 1.f / (float)nt, wh = 1.f / (float)nh, ww = 1.f / (float)nw;
    double rv = t * (double)wt * (double)wh * (double)ww;
    rest64[(size_t)n * 64 + c] = rv;
    float rv32 = (float)rv;
    float hi; short h = bf16rne(rv32, &hi);
    float hi2; short l = bf16rne(rv32 - hi, &hi2);
    int pt = n >> 4, m = n & 15, hf = c >> 5, q = (c >> 3) & 3, ii = c & 7;
    size_t slot = ((size_t)(((pt * 2 + hf) * 64) + q * 16 + m)) * 8 + ii;
    rhf[slot] = h; rlf[slot] = l;
  }
}

// ------------------------------------------- argmin pass 1 (bf16 MFMA GEMM)
// grid (NSpad/64, 16): 64 points (4 waves x 16p) x 1024-code chunk.
// 8 stripes of 128 j; per stripe 8 j-tiles x 2 k-halves x 3 split-MFMAs.
// dist = esq[j] - 2*dot; per-lane top-2 over its j-columns, quad-shfl merge.
__global__ __launch_bounds__(256) void argmin_kernel(
    const short* __restrict__ rhf, const short* __restrict__ rlf,
    const short* __restrict__ ehf, const short* __restrict__ elf,
    const float* __restrict__ esq, float4* __restrict__ part)
{
  __shared__ short8 Ah[4][2][64];   // [pt][hf][lane] 8KB
  __shared__ short8 Al[4][2][64];   // 8KB
  __shared__ short8 Bh[8][2][64];   // [jt][hf][lane] 16KB
  __shared__ short8 Bl[8][2][64];   // 16KB
  __shared__ float esql[128];
  int tid = threadIdx.x;
  int pbase = blockIdx.x * 64;
  int ch = blockIdx.y;
  {  // stage A frags: pure linear copy (coalesced global, canonical LDS)
    const short8* sH = (const short8*)(rhf + (size_t)pbase * 64);
    const short8* sL = (const short8*)(rlf + (size_t)pbase * 64);
    short8* dH = (short8*)Ah; short8* dL = (short8*)Al;
    dH[tid] = sH[tid]; dH[tid + 256] = sH[tid + 256];
    dL[tid] = sL[tid]; dL[tid + 256] = sL[tid + 256];
  }
  __syncthreads();
  int w = tid >> 6, lane = tid & 63, col = lane & 15;
  short8 ah0 = Ah[w][0][lane], ah1 = Ah[w][1][lane];
  short8 al0 = Al[w][0][lane], al1 = Al[w][1][lane];
  float m1[4], m2[4]; int i1[4];
#pragma unroll
  for (int r = 0; r < 4; r++) { m1[r] = 3.4e38f; m2[r] = 3.4e38f; i1[r] = 0x7fffffff; }
  for (int s = 0; s < 8; s++) {
    int j0 = ch * 1024 + s * 128;
    __syncthreads();
    {  // stage B frags for 128-j stripe: linear copy
      const short8* sH = (const short8*)(ehf + (size_t)j0 * 64);
      const short8* sL = (const short8*)(elf + (size_t)j0 * 64);
      short8* dH = (short8*)Bh; short8* dL = (short8*)Bl;
#pragma unroll
      for (int it = 0; it < 4; it++) { dH[tid + it * 256] = sH[tid + it * 256]; dL[tid + it * 256] = sL[tid + it * 256]; }
      if (tid < 128) esql[tid] = esq[j0 + tid];
    }
    __syncthreads();
    floatx4 acc[8];
#pragma unroll
    for (int jt = 0; jt < 8; jt++) acc[jt] = (floatx4){0.f, 0.f, 0.f, 0.f};
#pragma unroll
    for (int jt = 0; jt < 8; jt++) {
      short8 bh0 = Bh[jt][0][lane], bl0 = Bl[jt][0][lane];
      short8 bh1 = Bh[jt][1][lane], bl1 = Bl[jt][1][lane];
      acc[jt] = __builtin_amdgcn_mfma_f32_16x16x32_bf16(al0, bh0, acc[jt], 0, 0, 0);
      acc[jt] = __builtin_amdgcn_mfma_f32_16x16x32_bf16(ah0, bl0, acc[jt], 0, 0, 0);
      acc[jt] = __builtin_amdgcn_mfma_f32_16x16x32_bf16(ah0, bh0, acc[jt], 0, 0, 0);
      acc[jt] = __builtin_amdgcn_mfma_f32_16x16x32_bf16(al1, bh1, acc[jt], 0, 0, 0);
      acc[jt] = __builtin_amdgcn_mfma_f32_16x16x32_bf16(ah1, bl1, acc[jt], 0, 0, 0);
      acc[jt] = __builtin_amdgcn_mfma_f32_16x16x32_bf16(ah1, bh1, acc[jt], 0, 0, 0);
    }
#pragma unroll
    for (int jt = 0; jt < 8; jt++) {
      float es = esql[jt * 16 + col];
      int j = j0 + jt * 16 + col;
#pragma unroll
      for (int r = 0; r < 4; r++) {
        float d = fmaf(-2.f, acc[jt][r], es);  // ||z||^2 shift argmin-invariant
        if (d < m1[r]) { m2[r] = m1[r]; m1[r] = d; i1[r] = j; }
        else if (d < m2[r]) { m2[r] = d; }
      }
    }
  }
  // top-2 merge across the 16 lanes of each quad (rows stay within quad)
#pragma unroll
  for (int off = 1; off < 16; off <<= 1) {
#pragma unroll
    for (int r = 0; r < 4; r++) {
      float o1 = __shfl_xor(m1[r], off);
      int   oi = __shfl_xor(i1[r], off);
      float o2 = __shfl_xor(m2[r], off);
      bool bwin = (o1 < m1[r]) || (o1 == m1[r] && oi < i1[r]);
      float nm2 = bwin ? fminf(m1[r], o2) : fminf(m2[r], o1);
      if (bwin) { m1[r] = o1; i1[r] = oi; }
      m2[r] = nm2;
    }
  }
  if (col == 0) {
    int quad = lane >> 4;
#pragma unroll
    for (int r = 0; r < 4; r++) {
      int p = pbase + w * 16 + quad * 4 + r;
      part[(size_t)ch * NSP + p] = make_float4(m1[r], m2[r], __int_as_float(i1[r]), 0.f);
    }
  }
}

// ---------------------------- merge chunks, flag near-ties to global list
__global__ __launch_bounds__(256) void reduce_kernel(
    const float4* __restrict__ part, int* __restrict__ idx_cur,
    float* __restrict__ out_idx, int* flagcnt, int* flaglist, int N)
{
  int n = blockIdx.x * 256 + threadIdx.x;
  if (n >= N) return;
  float m1 = 3.4e38f, m2 = 3.4e38f; int i1 = 0x7fffffff;
  for (int ch = 0; ch < 16; ch++) {
    float4 q = part[(size_t)ch * NSP + n];
    float o1 = q.x, o2 = q.y; int oi = __float_as_int(q.z);
    bool bwin = (o1 < m1) || (o1 == m1 && oi < i1);
    float nm2 = bwin ? fminf(m1, o2) : fminf(m2, o1);
    if (bwin) { m1 = o1; i1 = oi; }
    m2 = nm2;
  }
  idx_cur[n] = i1;
  out_idx[n] = (float)i1;
  if (m2 - m1 < 0.01f) {  // near-tie vs split-bf16 noise (~7e-4): fp64 rescan
    int pos = atomicAdd(flagcnt, 1);
    flaglist[pos] = n;
  }
}

// -------------------- parallel fp64 rescan: block = (flag, 4096-code chunk)
__global__ __launch_bounds__(256) void refine_kernel(
    const double* __restrict__ rest64, const float* __restrict__ emb,
    const int* __restrict__ flagcnt, const int* __restrict__ flaglist,
    PBest* __restrict__ pbest)
{
  __shared__ double rl[64];
  __shared__ double bm[256];
  __shared__ int    bi[256];
  int f = blockIdx.x;
  if (f >= *flagcnt) return;
  int ch = blockIdx.y;
  int tid = threadIdx.x;
  int n = flaglist[f];
  if (tid < 64) rl[tid] = rest64[(size_t)n * 64 + tid];
  __syncthreads();
  double best = 1e300; int bidx = 0x7fffffff;
  for (int k = 0; k < 16; k++) {
    int j = ch * 4096 + k * 256 + tid;
    double d = 0.0;
    for (int c = 0; c < 64; c++) { double df = rl[c] - (double)emb[(size_t)j * 64 + c]; d += df * df; }
    if (d < best) { best = d; bidx = j; }  // ascending j keeps first min
  }
  bm[tid] = best; bi[tid] = bidx;
  __syncthreads();
  for (int s = 128; s > 0; s >>= 1) {
    if (tid < s) {
      double ob = bm[tid + s]; int oi = bi[tid + s];
      if (ob < bm[tid] || (ob == bm[tid] && oi < bi[tid])) { bm[tid] = ob; bi[tid] = oi; }
    }
    __syncthreads();
  }
  if (tid == 0) { pbest[f * 4 + ch].d = bm[0]; pbest[f * 4 + ch].idx = bi[0]; }
}

// -------------------------------- fold 4 chunk results per flagged point
__global__ __launch_bounds__(256) void refine_merge_kernel(
    const PBest* __restrict__ pbest, const int* __restrict__ flagcnt,
    const int* __restrict__ flaglist, int* __restrict__ idx_cur,
    float* __restrict__ out_idx)
{
  int f = blockIdx.x * 256 + threadIdx.x;
  if (f >= *flagcnt) return;
  double best = 1e300; int bidx = 0x7fffffff;
  for (int ch = 0; ch < 4; ch++) {  // ascending chunk keeps first min
    double d = pbest[f * 4 + ch].d; int j = pbest[f * 4 + ch].idx;
    if (d < best || (d == best && j < bidx)) { best = d; bidx = j; }
  }
  int n = flaglist[f];
  idx_cur[n] = bidx;
  out_idx[n] = (float)bidx;
}

// ------------------------------------------------------- trilinear upsample
__device__ inline void axis_map(int L, int outlen, int i, int* j0, int* j1, float* a0, float* a1) {
  if (L == 1) { *j0 = 0; *j1 = 0; *a0 = 1.f; *a1 = 0.f; return; }
  double scale = (double)L / (double)outlen;
  double src = (i + 0.5) * scale - 0.5;
  if (src < 0.0) src = 0.0;
  int i0 = (int)floor(src); if (i0 > L - 1) i0 = L - 1;
  int i1 = i0 + 1; if (i1 > L - 1) i1 = L - 1;
  double wv = src - (double)i0;
  if (i0 == i1) {
    float p = (float)(1.0 - wv), q = (float)wv;  // fp32 += emulation
    *a0 = p + q; *a1 = 0.f;
  } else { *a0 = (float)(1.0 - wv); *a1 = (float)wv; }
  *j0 = i0; *j1 = i1;
}

__global__ __launch_bounds__(256) void upsample_kernel(
    const float* __restrict__ emb, const int* __restrict__ idx_cur,
    double* __restrict__ hup, int tpn, int pn)
{
  int e = blockIdx.x * 256 + threadIdx.x;  // [b][t][h][w][c]
  int c = e & 63, w = (e >> 6) & 15, h = (e >> 10) & 15, t = (e >> 14) & 3, b = e >> 16;
  int t0, t1, h0, h1, w0, w1; float ta0, ta1, ha0, ha1, wa0, wa1;
  axis_map(tpn, 4, t, &t0, &t1, &ta0, &ta1);
  axis_map(pn, 16, h, &h0, &h1, &ha0, &ha1);
  axis_map(pn, 16, w, &w0, &w1, &wa0, &wa1);
  int ti[2] = {t0, t1}; float ta[2] = {ta0, ta1};
  int hi[2] = {h0, h1}; float ha[2] = {ha0, ha1};
  int wi[2] = {w0, w1}; float wa[2] = {wa0, wa1};
  double val = 0.0;
  for (int a = 0; a < 2; a++)
    for (int bb = 0; bb < 2; bb++)
      for (int cc = 0; cc < 2; cc++) {
        double wgt = (double)ta[a] * (double)ha[bb] * (double)wa[cc];
        if (wgt != 0.0) {
          int code = idx_cur[((b * tpn + ti[a]) * pn + hi[bb]) * pn + wi[cc]];
          val += wgt * (double)emb[(size_t)code * 64 + c];
        }
      }
  hup[e] = val;
}

// ------------------------------------------- conv3d + accu update + commit
__global__ __launch_bounds__(256) void conv_kernel(
    const double* __restrict__ hup, const float* __restrict__ twt, const float* __restrict__ bq,
    const float* __restrict__ zcl, double* __restrict__ accu, double* sse, int qi)
{
  __shared__ double hl[3][4][4][18];              // [tt][hh][cc][ww] halo, ci-chunk 4
  __shared__ __align__(16) float wl[27][4][64];   // [tap][cc][co] fp32 (exact)
  __shared__ double red[256];
  int bid = blockIdx.x;
  int b = bid >> 5, t = (bid >> 3) & 3, hq = bid & 7;
  int tid = threadIdx.x;
  int co4 = tid >> 4;  // co = co4*4 .. +3
  int w = tid & 15;
  double acc[2][4];
  for (int k = 0; k < 2; k++) for (int q = 0; q < 4; q++) acc[k][q] = 0.0;
  for (int ci0 = 0; ci0 < 64; ci0 += 4) {
    __syncthreads();
    for (int i = tid; i < 864; i += 256) {
      int ww = i % 18; int r = i / 18; int cc = r & 3; r >>= 2; int hh = r & 3; int tt = r >> 2;
      int gt = t - 1 + tt, gh = hq * 2 - 1 + hh, gw = ww - 1;
      double v = 0.0;
      if (gt >= 0 && gt < 4 && gh >= 0 && gh < 16 && gw >= 0 && gw < 16)
        v = hup[(size_t)((((b * 4 + gt) * 16 + gh) * 16 + gw) * 64 + ci0 + cc)];
      hl[tt][hh][cc][ww] = v;
    }
    for (int i = tid; i < 6912; i += 256) {
      int co = i & 63; int r = i >> 6; int cc = r & 3; int tap = r >> 2;
      wl[tap][cc][co] = twt[(size_t)(((qi * 27 + tap) * 64 + ci0 + cc) * 64 + co)];
    }
    __syncthreads();
    for (int tap = 0; tap < 27; tap++) {
      int dt = tap / 9, dh = (tap / 3) % 3, dw = tap % 3;
#pragma unroll
      for (int cc = 0; cc < 4; cc++) {
        float4 wf = *(const float4*)&wl[tap][cc][co4 * 4];
        double w0 = (double)wf.x, w1 = (double)wf.y, w2 = (double)wf.z, w3 = (double)wf.w;
#pragma unroll
        for (int k = 0; k < 2; k++) {
          double hv = hl[dt][k + dh][cc][w + dw];
          acc[k][0] += hv * w0; acc[k][1] += hv * w1;
          acc[k][2] += hv * w2; acc[k][3] += hv * w3;
        }
      }
    }
  }
  double lsse = 0.0;
  for (int k = 0; k < 2; k++) {
    int gh = hq * 2 + k;
    for (int q = 0; q < 4; q++) {
      int co = co4 * 4 + q;
      size_t off = (size_t)((((b * 4 + t) * 16 + gh) * 16 + w) * 64 + co);
      double conv = acc[k][q] + (double)bq[qi * 64 + co];
      double hu = hup[off];
      double na = accu[off] + 0.5 * hu + 0.5 * conv;  // h*(1-q) + conv*q, q=0.5
      accu[off] = na;
      double df = na - (double)zcl[off];
      lsse += df * df;
    }
  }
  red[tid] = lsse;
  __syncthreads();
  for (int s = 128; s > 0; s >>= 1) { if (tid < s) red[tid] += red[tid + s]; __syncthreads(); }
  if (tid == 0) atomicAdd(sse, red[0]);
}

// ---------------------------------------------------------------- stats
__global__ __launch_bounds__(256) void bincount_kernel(const int* __restrict__ idx_cur, int* counts) {
  int i = blockIdx.x * 256 + threadIdx.x;
  if (i < NSP) atomicAdd(&counts[idx_cur[i]], 1);
}

__global__ __launch_bounds__(256) void stats_kernel(
    const int* __restrict__ counts, float* __restrict__ usage_out, double* ent, int* usedcnt)
{
  __shared__ double re[256];
  __shared__ int ru[256];
  int j = blockIdx.x * 256 + threadIdx.x;
  int cnt = counts[j];
  double p = (double)cnt / 8192.0;
  usage_out[j] = (float)p;
  re[threadIdx.x] = p * log(p + 1e-10);
  ru[threadIdx.x] = cnt > 0 ? 1 : 0;
  __syncthreads();
  for (int s = 128; s > 0; s >>= 1) {
    if (threadIdx.x < s) { re[threadIdx.x] += re[threadIdx.x + s]; ru[threadIdx.x] += ru[threadIdx.x + s]; }
    __syncthreads();
  }
  if (threadIdx.x == 0) { atomicAdd(ent, re[0]); atomicAdd(usedcnt, ru[0]); }
}

__global__ void final_kernel(const double* sse, const double* ent, const int* usedcnt, float* out) {
  if (threadIdx.x == 0) {
    out[NELEM]     = (float)(*sse * 0.25 / 524288.0 / 10.0);
    out[NELEM + 1] = (float)exp(-*ent);
    out[NELEM + 2] = (float)((double)*usedcnt / 16384.0);
  }
}

__global__ __launch_bounds__(256) void embst_kernel(const double* __restrict__ accu, float* __restrict__ out) {
  int e = blockIdx.x * 256 + threadIdx.x;  // out [B,C,T,H,W]
  int w = e & 15, h = (e >> 4) & 15, t = (e >> 8) & 3, c = (e >> 10) & 63, b = e >> 16;
  out[e] = (float)accu[(size_t)(((((b * 4 + t) * 16 + h) * 16 + w) * 64) + c)];
}

// ---------------------------------------------------------------- launch
extern "C" void kernel_launch(void* const* d_in, const int* in_sizes, int n_in,
                              void* d_out, int out_size, void* d_ws, size_t ws_size,
                              hipStream_t stream) {
  static const int T_PN_h[10] = {1, 1, 2, 2, 2, 4, 4, 4, 4, 4};
  static const int V_PN_h[10] = {1, 2, 3, 4, 5, 6, 8, 10, 13, 16};
  // qi from bit-exact fp64 emulation of np.linspace+argmin (ties: si=2->1, si=7->3)
  static const int QI_h[10]   = {0, 0, 1, 1, 1, 2, 2, 3, 3, 3};
  static const int NS_h[10]   = {8, 32, 144, 256, 400, 1152, 2048, 3200, 5408, 8192};
  static const int OB_h[10]   = {540675, 540683, 540715, 540859, 541115,
                                 541515, 542667, 544715, 547915, 553323};

  const float* z   = (const float*)d_in[0];
  const float* emb = (const float*)d_in[1];
  const float* Wq  = (const float*)d_in[2];
  const float* bq  = (const float*)d_in[3];
  float* out = (float*)d_out;
  char* ws = (char*)d_ws;

  double* accu    = (double*)(ws + WS_ACCU);
  double* hup     = (double*)(ws + WS_HUP);
  double* rest64  = (double*)(ws + WS_REST64);
  float4* part    = (float4*)(ws + WS_PART);
  PBest*  pbest   = (PBest*)(ws + WS_PART);   // alias: part dead when pbest written
  float*  zcl     = (float*)(ws + WS_ZCL);
  short*  ehf     = (short*)(ws + WS_EHF);
  short*  elf     = (short*)(ws + WS_ELF);
  float*  esq     = (float*)(ws + WS_ESQ);
  float*  twt     = (float*)(ws + WS_TWT);
  int*    idx_cur = (int*)(ws + WS_IDX);
  int*    counts  = (int*)(ws + WS_CNT);
  int*    flaglist= (int*)(ws + WS_FLAGL);
  int*    flagcnt = (int*)(ws + WS_FLAGC);
  double* sse     = (double*)(ws + WS_SSE);
  double* ent     = (double*)(ws + WS_ENT);
  int*    usedcnt = (int*)(ws + WS_USED);
  short*  rhf     = (short*)(ws + WS_RHF);
  short*  rlf     = (short*)(ws + WS_RLF);

  prep_kernel<<<10049, 256, 0, stream>>>(z, emb, Wq, accu, zcl, ehf, elf, esq, twt,
                                         counts, flagcnt, sse, ent, usedcnt);

  for (int si = 0; si < 10; si++) {
    int tpn = T_PN_h[si], pn = V_PN_h[si], N = NS_h[si];
    int NSpad = (N + 63) & ~63;
    pool_kernel<<<NSpad, 256, 0, stream>>>(zcl, accu, rest64, rhf, rlf, N, tpn, pn);
    dim3 ag(NSpad / 64, 16);
    argmin_kernel<<<ag, 256, 0, stream>>>(rhf, rlf, ehf, elf, esq, part);
    reduce_kernel<<<(N + 255) / 256, 256, 0, stream>>>(part, idx_cur, out + OB_h[si],
                                                       flagcnt + si, flaglist, N);
    dim3 rg(N, 4);   // flags <= N; idle blocks exit on flagcnt read
    refine_kernel<<<rg, 256, 0, stream>>>(rest64, emb, flagcnt + si, flaglist, pbest);
    refine_merge_kernel<<<(N + 255) / 256, 256, 0, stream>>>(pbest, flagcnt + si, flaglist,
                                                             idx_cur, out + OB_h[si]);
    upsample_kernel<<<NELEM / 256, 256, 0, stream>>>(emb, idx_cur, hup, tpn, pn);
    conv_kernel<<<256, 256, 0, stream>>>(hup, twt, bq, zcl, accu, sse, QI_h[si]);
  }

  bincount_kernel<<<32, 256, 0, stream>>>(idx_cur, counts);
  stats_kernel<<<64, 256, 0, stream>>>(counts, out + 524291, ent, usedcnt);
  final_kernel<<<1, 64, 0, stream>>>(sse, ent, usedcnt, out);
  embst_kernel<<<NELEM / 256, 256, 0, stream>>>(accu, out);
}